// Round 1
// baseline (5440.159 us; speedup 1.0000x reference)
//
#include <hip/hip_runtime.h>
#include <hip/hip_bf16.h>
#include <math.h>

#define BS 16
#define C 192
#define H 120
#define W 120
#define HW 14400
#define AN 36
#define MID 18
#define CPG 64
#define EPS 1e-5f

// ---------------- pool6: x (b,c,120,120) -> P (b,c,36) ----------------
__global__ __launch_bounds__(256) void k_pool(const float* __restrict__ x,
                                              float* __restrict__ P) {
    int bc = blockIdx.x;                    // b*C + ch
    const float* xp = x + (size_t)bc * HW;
    __shared__ float acc[AN];
    int tid = threadIdx.x;
    if (tid < AN) acc[tid] = 0.f;
    __syncthreads();
    // 720 segments of 20 contiguous floats
    for (int s = tid; s < 720; s += 256) {
        int y = s / 6, xs = s % 6;
        const float4* p4 = (const float4*)(xp + y * W + xs * 20);
        float sum = 0.f;
        #pragma unroll
        for (int i = 0; i < 5; ++i) {
            float4 v = p4[i];
            sum += v.x + v.y + v.z + v.w;
        }
        atomicAdd(&acc[(y / 20) * 6 + xs], sum);
    }
    __syncthreads();
    if (tid < AN) P[(size_t)bc * AN + tid] = acc[tid] * (1.f / 400.f);
}

// ---------------- v = val_w (192x192) * P (per b) ----------------
__global__ __launch_bounds__(256) void k_val(const float* __restrict__ valw,
                                             const float* __restrict__ P,
                                             float* __restrict__ V) {
    int b = blockIdx.x;
    __shared__ float Pl[C * AN];
    int tid = threadIdx.x;
    for (int i = tid; i < C * AN; i += 256) Pl[i] = P[(size_t)b * C * AN + i];
    __syncthreads();
    for (int o = tid; o < C * AN; o += 256) {
        int cc = o / AN, a = o % AN;
        float s = 0.f;
        for (int k = 0; k < C; ++k) s += valw[cc * C + k] * Pl[k * AN + a];
        V[(size_t)b * C * AN + o] = s;
    }
}

// ------------- grouped 3x3 conv + BN1 + ReLU -> k1 (stored in d_out) -------------
__global__ __launch_bounds__(256) void k_conv(const float* __restrict__ x,
                                              const float* __restrict__ kw,
                                              const float* __restrict__ g1,
                                              const float* __restrict__ b1,
                                              const float* __restrict__ m1,
                                              const float* __restrict__ v1,
                                              float* __restrict__ k1) {
    int bc = blockIdx.x;                    // b*C + co
    int b = bc / C, co = bc % C;
    int grp = co / CPG;
    float inv = g1[co] * rsqrtf(v1[co] + EPS);
    float beta = b1[co] - m1[co] * inv;
    __shared__ float wl[CPG * 9];
    int tid = threadIdx.x;
    for (int i = tid; i < CPG * 9; i += 256)
        wl[i] = kw[(size_t)co * CPG * 9 + i] * inv;
    __syncthreads();
    const float* xg = x + ((size_t)b * C + grp * CPG) * HW;
    float* outp = k1 + (size_t)bc * HW;
    for (int s = tid; s < 1800; s += 256) {      // 8-wide output strips
        int y = s / 15, x0 = (s % 15) * 8;
        float acc[8];
        #pragma unroll
        for (int p = 0; p < 8; ++p) acc[p] = 0.f;
        for (int ci = 0; ci < CPG; ++ci) {
            const float* xr = xg + (size_t)ci * HW;
            #pragma unroll
            for (int ky = 0; ky < 3; ++ky) {
                int yy = y + ky - 1;
                if (yy < 0 || yy >= H) continue;     // zero padding
                const float* row = xr + yy * W;
                float r[10];
                r[0] = (x0 > 0) ? row[x0 - 1] : 0.f;
                float4 a0 = *(const float4*)(row + x0);
                float4 a1 = *(const float4*)(row + x0 + 4);
                r[1] = a0.x; r[2] = a0.y; r[3] = a0.z; r[4] = a0.w;
                r[5] = a1.x; r[6] = a1.y; r[7] = a1.z; r[8] = a1.w;
                r[9] = (x0 < 112) ? row[x0 + 8] : 0.f;
                #pragma unroll
                for (int kx = 0; kx < 3; ++kx) {
                    float wv = wl[ci * 9 + ky * 3 + kx];
                    #pragma unroll
                    for (int p = 0; p < 8; ++p) acc[p] += wv * r[p + kx];
                }
            }
        }
        float res[8];
        #pragma unroll
        for (int p = 0; p < 8; ++p) {
            float t = acc[p] + beta;
            res[p] = t > 0.f ? t : 0.f;
        }
        *(float4*)(outp + y * W + x0) = make_float4(res[0], res[1], res[2], res[3]);
        *(float4*)(outp + y * W + x0 + 4) = make_float4(res[4], res[5], res[6], res[7]);
    }
}

// ------- scores: S1[b,a,n] = agent·k1r,  S2[b,a,n] = agent·q1 (=q_attn pre-softmax, transposed) -------
__global__ __launch_bounds__(256) void k_scores(const float* __restrict__ P,
                                                const float* __restrict__ k1,
                                                const float* __restrict__ x,
                                                float* __restrict__ S1,
                                                float* __restrict__ S2) {
    int b = blockIdx.y;
    int n0 = blockIdx.x * 64;
    __shared__ float G[C * AN];       // agent[b] flat: G[a*192+cc]
    __shared__ float Bt[64 * C];      // 64 pixel-rows of 192
    int tid = threadIdx.x;
    for (int i = tid; i < C * AN; i += 256) G[i] = P[(size_t)b * C * AN + i];
    const float* src = k1 + (size_t)b * C * HW + (size_t)n0 * C;
    for (int i = tid; i < 64 * C / 4; i += 256)
        ((float4*)Bt)[i] = ((const float4*)src)[i];
    __syncthreads();
    int ag = tid >> 6, px = tid & 63;     // 4 a-groups x 64 pixels
    float acc[9];
    #pragma unroll
    for (int q = 0; q < 9; ++q) acc[q] = 0.f;
    for (int cc = 0; cc < C; cc += 4) {
        float4 bv = *(const float4*)(Bt + px * C + cc);
        #pragma unroll
        for (int q = 0; q < 9; ++q) {
            float4 gv = *(const float4*)(G + (ag * 9 + q) * C + cc);
            acc[q] += gv.x * bv.x + gv.y * bv.y + gv.z * bv.z + gv.w * bv.w;
        }
    }
    #pragma unroll
    for (int q = 0; q < 9; ++q)
        S1[((size_t)b * AN + ag * 9 + q) * HW + n0 + px] = acc[q];
    __syncthreads();
    const float* src2 = x + (size_t)b * C * HW + (size_t)n0 * C;
    for (int i = tid; i < 64 * C / 4; i += 256)
        ((float4*)Bt)[i] = ((const float4*)src2)[i];
    __syncthreads();
    #pragma unroll
    for (int q = 0; q < 9; ++q) acc[q] = 0.f;
    for (int cc = 0; cc < C; cc += 4) {
        float4 bv = *(const float4*)(Bt + px * C + cc);
        #pragma unroll
        for (int q = 0; q < 9; ++q) {
            float4 gv = *(const float4*)(G + (ag * 9 + q) * C + cc);
            acc[q] += gv.x * bv.x + gv.y * bv.y + gv.z * bv.z + gv.w * bv.w;
        }
    }
    #pragma unroll
    for (int q = 0; q < 9; ++q)
        S2[((size_t)b * AN + ag * 9 + q) * HW + n0 + px] = acc[q];
}

// ---------------- softmax over n (14400) per (b,a) row, in place ----------------
__global__ __launch_bounds__(256) void k_softmax_rows(float* __restrict__ S) {
    int row = blockIdx.x;
    float* p = S + (size_t)row * HW;
    int tid = threadIdx.x;
    __shared__ float red[4];
    float m = -1e30f;
    for (int i = tid; i < HW / 4; i += 256) {
        float4 v = ((const float4*)p)[i];
        m = fmaxf(m, fmaxf(fmaxf(v.x, v.y), fmaxf(v.z, v.w)));
    }
    #pragma unroll
    for (int off = 32; off > 0; off >>= 1) m = fmaxf(m, __shfl_down(m, off, 64));
    if ((tid & 63) == 0) red[tid >> 6] = m;
    __syncthreads();
    m = fmaxf(fmaxf(red[0], red[1]), fmaxf(red[2], red[3]));
    __syncthreads();
    float s = 0.f;
    for (int i = tid; i < HW / 4; i += 256) {
        float4 v = ((const float4*)p)[i];
        v.x = __expf(v.x - m); v.y = __expf(v.y - m);
        v.z = __expf(v.z - m); v.w = __expf(v.w - m);
        ((float4*)p)[i] = v;
        s += v.x + v.y + v.z + v.w;
    }
    #pragma unroll
    for (int off = 32; off > 0; off >>= 1) s += __shfl_down(s, off, 64);
    if ((tid & 63) == 0) red[tid >> 6] = s;
    __syncthreads();
    float inv = 1.f / (red[0] + red[1] + red[2] + red[3]);
    for (int i = tid; i < HW / 4; i += 256) {
        float4 v = ((float4*)p)[i];
        v.x *= inv; v.y *= inv; v.z *= inv; v.w *= inv;
        ((float4*)p)[i] = v;
    }
}

// ------- fused: y(col) -> conv1(BN2,ReLU) -> conv2(mean-folded) -> att_mean -------
__global__ __launch_bounds__(256) void k_fuse(const float* __restrict__ A1,
                                              const float* __restrict__ S2,
                                              const float* __restrict__ w1,
                                              const float* __restrict__ g2,
                                              const float* __restrict__ b2,
                                              const float* __restrict__ m2,
                                              const float* __restrict__ v2,
                                              const float* __restrict__ w2,
                                              const float* __restrict__ bias2,
                                              float* __restrict__ AM) {
    int b = blockIdx.y;
    int tid = threadIdx.x;
    int N = blockIdx.x * 256 + tid;
    __shared__ float W1f[MID * 72];
    __shared__ float b1f[MID];
    __shared__ float W2m[AN * MID];
    __shared__ float b2m[AN];
    for (int i = tid; i < MID * 72; i += 256) {
        int m = i / 72;
        W1f[i] = w1[i] * (g2[m] * rsqrtf(v2[m] + EPS));
    }
    if (tid < MID) {
        float inv = g2[tid] * rsqrtf(v2[tid] + EPS);
        b1f[tid] = b2[tid] - m2[tid] * inv;
    }
    for (int i = tid; i < AN * MID; i += 256) {
        int a = i / MID, m = i % MID;
        float s = 0.f;
        #pragma unroll
        for (int k = 0; k < 9; ++k) s += w2[(a * 9 + k) * MID + m];
        W2m[i] = s * (1.f / 9.f);
    }
    if (tid < AN) {
        float s = 0.f;
        #pragma unroll
        for (int k = 0; k < 9; ++k) s += bias2[tid * 9 + k];
        b2m[tid] = s * (1.f / 9.f);
    }
    __syncthreads();
    if (N >= HW) return;
    float yv[72];
    const float* a1p = A1 + (size_t)b * AN * HW + N;
    #pragma unroll
    for (int j = 0; j < AN; ++j) yv[j] = a1p[(size_t)j * HW];
    const float* s2p = S2 + (size_t)b * AN * HW + N;
    float mx = -1e30f;
    #pragma unroll
    for (int j = 0; j < AN; ++j) {
        float v = s2p[(size_t)j * HW];
        yv[AN + j] = v;
        mx = fmaxf(mx, v);
    }
    float ssum = 0.f;
    #pragma unroll
    for (int j = 0; j < AN; ++j) {
        float e = __expf(yv[AN + j] - mx);
        yv[AN + j] = e;
        ssum += e;
    }
    float rs = 1.f / ssum;
    #pragma unroll
    for (int j = 0; j < AN; ++j) yv[AN + j] *= rs;
    float t[MID];
    #pragma unroll
    for (int m = 0; m < MID; ++m) {
        float a = b1f[m];
        #pragma unroll
        for (int j = 0; j < 72; ++j) a += W1f[m * 72 + j] * yv[j];
        t[m] = a > 0.f ? a : 0.f;
    }
    float* amp = AM + (size_t)b * AN * HW + N;
    #pragma unroll
    for (int a = 0; a < AN; ++a) {
        float acc = b2m[a];
        #pragma unroll
        for (int m = 0; m < MID; ++m) acc += W2m[a * MID + m] * t[m];
        amp[(size_t)a * HW] = acc;
    }
}

// ------- out[b,cc,n] = sum_a softmax36(att_mean window)[a]*v[b,cc,a] + k1[b,cc,n] -------
__global__ __launch_bounds__(256) void k_out(const float* __restrict__ AM,
                                             const float* __restrict__ V,
                                             float* __restrict__ k1out) {
    int b = blockIdx.y;
    int tid = threadIdx.x;
    int N = blockIdx.x * 256 + tid;
    __shared__ float Vl[C * AN];
    for (int i = tid; i < C * AN; i += 256) Vl[i] = V[(size_t)b * C * AN + i];
    __syncthreads();
    if (N >= HW) return;
    int a = N / 400;
    int n0 = (N % 400) * AN;
    const float4* amr = (const float4*)(AM + ((size_t)b * AN + a) * HW + n0);
    float w[AN];
    float mx = -1e30f;
    #pragma unroll
    for (int i4 = 0; i4 < 9; ++i4) {
        float4 q = amr[i4];
        w[i4 * 4 + 0] = q.x; w[i4 * 4 + 1] = q.y;
        w[i4 * 4 + 2] = q.z; w[i4 * 4 + 3] = q.w;
    }
    #pragma unroll
    for (int i = 0; i < AN; ++i) mx = fmaxf(mx, w[i]);
    float s = 0.f;
    #pragma unroll
    for (int i = 0; i < AN; ++i) { w[i] = __expf(w[i] - mx); s += w[i]; }
    float rs = 1.f / s;
    #pragma unroll
    for (int i = 0; i < AN; ++i) w[i] *= rs;
    float* op = k1out + (size_t)b * C * HW + N;
    for (int cc = 0; cc < C; ++cc) {
        float acc = op[(size_t)cc * HW];          // k1 value (residual)
        const float* vr = Vl + cc * AN;
        #pragma unroll
        for (int i = 0; i < AN; ++i) acc += w[i] * vr[i];
        op[(size_t)cc * HW] = acc;
    }
}

extern "C" void kernel_launch(void* const* d_in, const int* in_sizes, int n_in,
                              void* d_out, int out_size, void* d_ws, size_t ws_size,
                              hipStream_t stream) {
    const float* x      = (const float*)d_in[0];
    const float* key_w  = (const float*)d_in[1];
    const float* bn1_g  = (const float*)d_in[2];
    const float* bn1_b  = (const float*)d_in[3];
    const float* bn1_m  = (const float*)d_in[4];
    const float* bn1_v  = (const float*)d_in[5];
    const float* val_w  = (const float*)d_in[6];
    const float* att_w1 = (const float*)d_in[7];
    const float* bn2_g  = (const float*)d_in[8];
    const float* bn2_b  = (const float*)d_in[9];
    const float* bn2_m  = (const float*)d_in[10];
    const float* bn2_v  = (const float*)d_in[11];
    const float* att_w2 = (const float*)d_in[12];
    const float* att_b2 = (const float*)d_in[13];
    float* out = (float*)d_out;                 // also holds k1 (177 MB)
    float* ws  = (float*)d_ws;

    float* P  = ws;                                   // BS*C*AN = 110592
    float* V  = P + (size_t)BS * C * AN;              // 110592
    float* S1 = V + (size_t)BS * C * AN;              // BS*AN*HW = 8294400
    float* S2 = S1 + (size_t)BS * AN * HW;            // 8294400
    float* AM = S2 + (size_t)BS * AN * HW;            // 8294400

    k_pool<<<BS * C, 256, 0, stream>>>(x, P);
    k_val<<<BS, 256, 0, stream>>>(val_w, P, V);
    k_conv<<<BS * C, 256, 0, stream>>>(x, key_w, bn1_g, bn1_b, bn1_m, bn1_v, out);
    k_scores<<<dim3(HW / 64, BS), 256, 0, stream>>>(P, out, x, S1, S2);
    k_softmax_rows<<<BS * AN, 256, 0, stream>>>(S1);
    k_fuse<<<dim3((HW + 255) / 256, BS), 256, 0, stream>>>(
        S1, S2, att_w1, bn2_g, bn2_b, bn2_m, bn2_v, att_w2, att_b2, AM);
    k_out<<<dim3((HW + 255) / 256, BS), 256, 0, stream>>>(AM, V, out);
}

// Round 2
// 781.437 us; speedup vs baseline: 6.9617x; 6.9617x over previous
//
#include <hip/hip_runtime.h>
#include <hip/hip_bf16.h>
#include <math.h>

#define BS 16
#define C 192
#define H 120
#define W 120
#define HW 14400
#define AN 36
#define MID 18
#define CPG 64
#define EPS 1e-5f

typedef __attribute__((ext_vector_type(8))) short s16x8;
typedef __attribute__((ext_vector_type(4))) float f32x4;

static __device__ __forceinline__ short f2bf(float f) {
    union { float f; unsigned u; } v; v.f = f;
    unsigned r = (v.u + 0x7FFF + ((v.u >> 16) & 1)) >> 16;
    return (short)r;
}

// ---------------- pool6: x (b,c,120,120) -> P (b,c,36) ----------------
__global__ __launch_bounds__(256) void k_pool(const float* __restrict__ x,
                                              float* __restrict__ P) {
    int bc = blockIdx.x;                    // b*C + ch
    const float* xp = x + (size_t)bc * HW;
    __shared__ float acc[AN];
    int tid = threadIdx.x;
    if (tid < AN) acc[tid] = 0.f;
    __syncthreads();
    for (int s = tid; s < 720; s += 256) {
        int y = s / 6, xs = s % 6;
        const float4* p4 = (const float4*)(xp + y * W + xs * 20);
        float sum = 0.f;
        #pragma unroll
        for (int i = 0; i < 5; ++i) {
            float4 v = p4[i];
            sum += v.x + v.y + v.z + v.w;
        }
        atomicAdd(&acc[(y / 20) * 6 + xs], sum);
    }
    __syncthreads();
    if (tid < AN) P[(size_t)bc * AN + tid] = acc[tid] * (1.f / 400.f);
}

// ---------------- v = val_w (192x192) * P (per b) ----------------
__global__ __launch_bounds__(256) void k_val(const float* __restrict__ valw,
                                             const float* __restrict__ P,
                                             float* __restrict__ V) {
    int b = blockIdx.x;
    __shared__ float Pl[C * AN];
    int tid = threadIdx.x;
    for (int i = tid; i < C * AN; i += 256) Pl[i] = P[(size_t)b * C * AN + i];
    __syncthreads();
    for (int o = tid; o < C * AN; o += 256) {
        int cc = o / AN, a = o % AN;
        float s = 0.f;
        for (int k = 0; k < C; ++k) s += valw[cc * C + k] * Pl[k * AN + a];
        V[(size_t)b * C * AN + o] = s;
    }
}

// ------------- grouped 3x3 conv + BN1 + ReLU via implicit-GEMM MFMA -------------
// block = (y-row, group, batch). out tile = 128 px (8 M-tiles) x 64 co (4 N-tiles).
// K = 64 ci * 9 taps, chunked as 2 ci-chunks of 32.
#define PXD 132
__global__ __launch_bounds__(256, 2) void k_conv_mfma(
        const float* __restrict__ x, const float* __restrict__ kw,
        const float* __restrict__ g1, const float* __restrict__ b1,
        const float* __restrict__ m1, const float* __restrict__ v1,
        float* __restrict__ k1) {
    int y = blockIdx.x, g = blockIdx.y, b = blockIdx.z;
    int t = threadIdx.x;
    __shared__ short xl[3 * PXD * 32];     // [row][padded px][ci32] bf16
    __shared__ short wl[9 * 64 * 32];      // [tap][co][ci32] bf16 (BN-scaled)

    int wv = t >> 6, l = t & 63;
    int lr = l & 15, hi = l >> 4;
    f32x4 acc[2][4];
    #pragma unroll
    for (int mt = 0; mt < 2; ++mt)
        #pragma unroll
        for (int nt = 0; nt < 4; ++nt)
            acc[mt][nt] = (f32x4){0.f, 0.f, 0.f, 0.f};

    int o = t & 3;          // ci octet for x staging
    int pxp = t >> 2;       // 0..63

    for (int cc = 0; cc < 2; ++cc) {
        int cc0 = cc * 32;
        // ---- stage x chunk: xl[r][p][ci] = bf16(x[ci][y+r-1][p-1]) ----
        #pragma unroll
        for (int r = 0; r < 3; ++r) {
            int yy = y + r - 1;
            bool rowok = (yy >= 0) && (yy < H);
            const float* xb = x + ((size_t)(b * C + g * CPG + cc0 + o * 8)) * HW + yy * W;
            #pragma unroll
            for (int pb = 0; pb < 3; ++pb) {
                int p = pxp + 64 * pb;
                if (p >= PXD) continue;
                int px = p - 1;
                s16x8 v = {0, 0, 0, 0, 0, 0, 0, 0};
                if (rowok && px >= 0 && px < W) {
                    #pragma unroll
                    for (int j = 0; j < 8; ++j) v[j] = f2bf(xb[(size_t)j * HW + px]);
                }
                *(s16x8*)&xl[((r * PXD) + p) * 32 + o * 8] = v;
            }
        }
        // ---- stage W chunk: wl[tap][co][ci] = bf16(kw[co][ci][tap] * inv[co]) ----
        #pragma unroll
        for (int it = 0; it < 8; ++it) {
            int idx = t + 256 * it;          // 0..2047
            int co = idx >> 5, ci = idx & 31;
            int cog = g * CPG + co;
            float inv = g1[cog] * rsqrtf(v1[cog] + EPS);
            const float* wp = kw + ((size_t)cog * CPG + cc0 + ci) * 9;
            #pragma unroll
            for (int tp = 0; tp < 9; ++tp)
                wl[(tp * 64 + co) * 32 + ci] = f2bf(wp[tp] * inv);
        }
        __syncthreads();
        // ---- 9 taps x 1 K-step each ----
        #pragma unroll
        for (int tap = 0; tap < 9; ++tap) {
            int ky = tap / 3, kx = tap % 3;
            s16x8 B[4];
            #pragma unroll
            for (int nt = 0; nt < 4; ++nt)
                B[nt] = *(const s16x8*)&wl[(tap * 64 + nt * 16 + lr) * 32 + hi * 8];
            s16x8 A[2];
            #pragma unroll
            for (int mt = 0; mt < 2; ++mt) {
                int pp = (wv * 2 + mt) * 16 + kx + lr;   // padded col
                A[mt] = *(const s16x8*)&xl[((ky * PXD) + pp) * 32 + hi * 8];
            }
            #pragma unroll
            for (int mt = 0; mt < 2; ++mt)
                #pragma unroll
                for (int nt = 0; nt < 4; ++nt)
                    acc[mt][nt] = __builtin_amdgcn_mfma_f32_16x16x32_bf16(
                        A[mt], B[nt], acc[mt][nt], 0, 0, 0);
        }
        __syncthreads();
    }
    // ---- epilogue: +beta, ReLU, store ----
    #pragma unroll
    for (int nt = 0; nt < 4; ++nt) {
        int cog = g * CPG + nt * 16 + lr;
        float inv = g1[cog] * rsqrtf(v1[cog] + EPS);
        float beta = b1[cog] - m1[cog] * inv;
        #pragma unroll
        for (int mt = 0; mt < 2; ++mt) {
            int px = (wv * 2 + mt) * 16 + hi * 4;
            if (px > 116) continue;
            float* op = k1 + ((size_t)(b * C + cog)) * HW + y * W + px;
            float4 r;
            r.x = fmaxf(acc[mt][nt][0] + beta, 0.f);
            r.y = fmaxf(acc[mt][nt][1] + beta, 0.f);
            r.z = fmaxf(acc[mt][nt][2] + beta, 0.f);
            r.w = fmaxf(acc[mt][nt][3] + beta, 0.f);
            *(float4*)op = r;
        }
    }
}

// ------- scores: S1[b,a,n] = agent·k1r,  S2[b,a,n] = agent·q1 -------
#define BTS 196
__global__ __launch_bounds__(256) void k_scores(const float* __restrict__ P,
                                                const float* __restrict__ k1,
                                                const float* __restrict__ x,
                                                float* __restrict__ S1,
                                                float* __restrict__ S2) {
    int b = blockIdx.y;
    int n0 = blockIdx.x * 64;
    __shared__ float G[C * AN];        // agent[b] flat: G[a*192+cc]
    __shared__ float Bt[64 * BTS];     // 64 pixel-rows of 192 (stride-padded)
    int tid = threadIdx.x;
    for (int i = tid; i < C * AN; i += 256) G[i] = P[(size_t)b * C * AN + i];
    const float* src = k1 + (size_t)b * C * HW + (size_t)n0 * C;
    for (int i = tid; i < 64 * 48; i += 256) {
        int row = i / 48, q4 = i % 48;
        *(float4*)(Bt + row * BTS + q4 * 4) = ((const float4*)src)[i];
    }
    __syncthreads();
    int ag = tid >> 6, px = tid & 63;
    float acc[9];
    #pragma unroll
    for (int q = 0; q < 9; ++q) acc[q] = 0.f;
    for (int cc = 0; cc < C; cc += 4) {
        float4 bv = *(const float4*)(Bt + px * BTS + cc);
        #pragma unroll
        for (int q = 0; q < 9; ++q) {
            const float4 gv = *(const float4*)(G + (ag * 9 + q) * C + cc);
            acc[q] += gv.x * bv.x + gv.y * bv.y + gv.z * bv.z + gv.w * bv.w;
        }
    }
    #pragma unroll
    for (int q = 0; q < 9; ++q)
        S1[((size_t)b * AN + ag * 9 + q) * HW + n0 + px] = acc[q];
    __syncthreads();
    const float* src2 = x + (size_t)b * C * HW + (size_t)n0 * C;
    for (int i = tid; i < 64 * 48; i += 256) {
        int row = i / 48, q4 = i % 48;
        *(float4*)(Bt + row * BTS + q4 * 4) = ((const float4*)src2)[i];
    }
    __syncthreads();
    #pragma unroll
    for (int q = 0; q < 9; ++q) acc[q] = 0.f;
    for (int cc = 0; cc < C; cc += 4) {
        float4 bv = *(const float4*)(Bt + px * BTS + cc);
        #pragma unroll
        for (int q = 0; q < 9; ++q) {
            const float4 gv = *(const float4*)(G + (ag * 9 + q) * C + cc);
            acc[q] += gv.x * bv.x + gv.y * bv.y + gv.z * bv.z + gv.w * bv.w;
        }
    }
    #pragma unroll
    for (int q = 0; q < 9; ++q)
        S2[((size_t)b * AN + ag * 9 + q) * HW + n0 + px] = acc[q];
}

// ---------------- softmax over n (14400) per (b,a) row, in place ----------------
__global__ __launch_bounds__(256) void k_softmax_rows(float* __restrict__ S) {
    int row = blockIdx.x;
    float* p = S + (size_t)row * HW;
    int tid = threadIdx.x;
    __shared__ float red[4];
    float m = -1e30f;
    for (int i = tid; i < HW / 4; i += 256) {
        float4 v = ((const float4*)p)[i];
        m = fmaxf(m, fmaxf(fmaxf(v.x, v.y), fmaxf(v.z, v.w)));
    }
    #pragma unroll
    for (int off = 32; off > 0; off >>= 1) m = fmaxf(m, __shfl_down(m, off, 64));
    if ((tid & 63) == 0) red[tid >> 6] = m;
    __syncthreads();
    m = fmaxf(fmaxf(red[0], red[1]), fmaxf(red[2], red[3]));
    __syncthreads();
    float s = 0.f;
    for (int i = tid; i < HW / 4; i += 256) {
        float4 v = ((const float4*)p)[i];
        v.x = __expf(v.x - m); v.y = __expf(v.y - m);
        v.z = __expf(v.z - m); v.w = __expf(v.w - m);
        ((float4*)p)[i] = v;
        s += v.x + v.y + v.z + v.w;
    }
    #pragma unroll
    for (int off = 32; off > 0; off >>= 1) s += __shfl_down(s, off, 64);
    if ((tid & 63) == 0) red[tid >> 6] = s;
    __syncthreads();
    float inv = 1.f / (red[0] + red[1] + red[2] + red[3]);
    for (int i = tid; i < HW / 4; i += 256) {
        float4 v = ((float4*)p)[i];
        v.x *= inv; v.y *= inv; v.z *= inv; v.w *= inv;
        ((float4*)p)[i] = v;
    }
}

// ------- fused: y(col) -> conv1(BN2,ReLU) -> conv2(mean-folded) -> att_mean -------
__global__ __launch_bounds__(256) void k_fuse(const float* __restrict__ A1,
                                              const float* __restrict__ S2,
                                              const float* __restrict__ w1,
                                              const float* __restrict__ g2,
                                              const float* __restrict__ b2,
                                              const float* __restrict__ m2,
                                              const float* __restrict__ v2,
                                              const float* __restrict__ w2,
                                              const float* __restrict__ bias2,
                                              float* __restrict__ AM) {
    int b = blockIdx.y;
    int tid = threadIdx.x;
    int N = blockIdx.x * 256 + tid;
    __shared__ float W1f[MID * 72];
    __shared__ float b1f[MID];
    __shared__ float W2m[AN * MID];
    __shared__ float b2m[AN];
    for (int i = tid; i < MID * 72; i += 256) {
        int m = i / 72;
        W1f[i] = w1[i] * (g2[m] * rsqrtf(v2[m] + EPS));
    }
    if (tid < MID) {
        float inv = g2[tid] * rsqrtf(v2[tid] + EPS);
        b1f[tid] = b2[tid] - m2[tid] * inv;
    }
    for (int i = tid; i < AN * MID; i += 256) {
        int a = i / MID, m = i % MID;
        float s = 0.f;
        #pragma unroll
        for (int k = 0; k < 9; ++k) s += w2[(a * 9 + k) * MID + m];
        W2m[i] = s * (1.f / 9.f);
    }
    if (tid < AN) {
        float s = 0.f;
        #pragma unroll
        for (int k = 0; k < 9; ++k) s += bias2[tid * 9 + k];
        b2m[tid] = s * (1.f / 9.f);
    }
    __syncthreads();
    if (N >= HW) return;
    float yv[72];
    const float* a1p = A1 + (size_t)b * AN * HW + N;
    #pragma unroll
    for (int j = 0; j < AN; ++j) yv[j] = a1p[(size_t)j * HW];
    const float* s2p = S2 + (size_t)b * AN * HW + N;
    float mx = -1e30f;
    #pragma unroll
    for (int j = 0; j < AN; ++j) {
        float v = s2p[(size_t)j * HW];
        yv[AN + j] = v;
        mx = fmaxf(mx, v);
    }
    float ssum = 0.f;
    #pragma unroll
    for (int j = 0; j < AN; ++j) {
        float e = __expf(yv[AN + j] - mx);
        yv[AN + j] = e;
        ssum += e;
    }
    float rs = 1.f / ssum;
    #pragma unroll
    for (int j = 0; j < AN; ++j) yv[AN + j] *= rs;
    float t[MID];
    #pragma unroll
    for (int m = 0; m < MID; ++m) {
        float a = b1f[m];
        #pragma unroll
        for (int j = 0; j < 72; ++j) a += W1f[m * 72 + j] * yv[j];
        t[m] = a > 0.f ? a : 0.f;
    }
    float* amp = AM + (size_t)b * AN * HW + N;
    #pragma unroll
    for (int a = 0; a < AN; ++a) {
        float acc = b2m[a];
        #pragma unroll
        for (int m = 0; m < MID; ++m) acc += W2m[a * MID + m] * t[m];
        amp[(size_t)a * HW] = acc;
    }
}

// ------- out[b,cc,n] = sum_a softmax36(att window)[a]*v[b,cc,a] + k1[b,cc,n] -------
__global__ __launch_bounds__(256) void k_out(const float* __restrict__ AM,
                                             const float* __restrict__ V,
                                             float* __restrict__ k1out) {
    int b = blockIdx.y;
    int tid = threadIdx.x;
    int N = blockIdx.x * 256 + tid;
    __shared__ float Vl[C * AN];
    for (int i = tid; i < C * AN; i += 256) Vl[i] = V[(size_t)b * C * AN + i];
    __syncthreads();
    if (N >= HW) return;
    int a = N / 400;
    int n0 = (N % 400) * AN;
    const float4* amr = (const float4*)(AM + ((size_t)b * AN + a) * HW + n0);
    float w[AN];
    float mx = -1e30f;
    #pragma unroll
    for (int i4 = 0; i4 < 9; ++i4) {
        float4 q = amr[i4];
        w[i4 * 4 + 0] = q.x; w[i4 * 4 + 1] = q.y;
        w[i4 * 4 + 2] = q.z; w[i4 * 4 + 3] = q.w;
    }
    #pragma unroll
    for (int i = 0; i < AN; ++i) mx = fmaxf(mx, w[i]);
    float s = 0.f;
    #pragma unroll
    for (int i = 0; i < AN; ++i) { w[i] = __expf(w[i] - mx); s += w[i]; }
    float rs = 1.f / s;
    #pragma unroll
    for (int i = 0; i < AN; ++i) w[i] *= rs;
    float* op = k1out + (size_t)b * C * HW + N;
    for (int cc = 0; cc < C; ++cc) {
        float acc = op[(size_t)cc * HW];
        const float* vr = Vl + cc * AN;
        #pragma unroll
        for (int i = 0; i < AN; ++i) acc += w[i] * vr[i];
        op[(size_t)cc * HW] = acc;
    }
}

extern "C" void kernel_launch(void* const* d_in, const int* in_sizes, int n_in,
                              void* d_out, int out_size, void* d_ws, size_t ws_size,
                              hipStream_t stream) {
    const float* x      = (const float*)d_in[0];
    const float* key_w  = (const float*)d_in[1];
    const float* bn1_g  = (const float*)d_in[2];
    const float* bn1_b  = (const float*)d_in[3];
    const float* bn1_m  = (const float*)d_in[4];
    const float* bn1_v  = (const float*)d_in[5];
    const float* val_w  = (const float*)d_in[6];
    const float* att_w1 = (const float*)d_in[7];
    const float* bn2_g  = (const float*)d_in[8];
    const float* bn2_b  = (const float*)d_in[9];
    const float* bn2_m  = (const float*)d_in[10];
    const float* bn2_v  = (const float*)d_in[11];
    const float* att_w2 = (const float*)d_in[12];
    const float* att_b2 = (const float*)d_in[13];
    float* out = (float*)d_out;                 // also holds k1
    float* ws  = (float*)d_ws;

    float* P  = ws;
    float* V  = P + (size_t)BS * C * AN;
    float* S1 = V + (size_t)BS * C * AN;
    float* S2 = S1 + (size_t)BS * AN * HW;
    float* AM = S2 + (size_t)BS * AN * HW;

    k_pool<<<BS * C, 256, 0, stream>>>(x, P);
    k_val<<<BS, 256, 0, stream>>>(val_w, P, V);
    k_conv_mfma<<<dim3(H, 3, BS), 256, 0, stream>>>(x, key_w, bn1_g, bn1_b, bn1_m, bn1_v, out);
    k_scores<<<dim3(HW / 64, BS), 256, 0, stream>>>(P, out, x, S1, S2);
    k_softmax_rows<<<BS * AN, 256, 0, stream>>>(S1);
    k_fuse<<<dim3((HW + 255) / 256, BS), 256, 0, stream>>>(
        S1, S2, att_w1, bn2_g, bn2_b, bn2_m, bn2_v, att_w2, att_b2, AM);
    k_out<<<dim3((HW + 255) / 256, BS), 256, 0, stream>>>(AM, V, out);
}

// Round 3
// 662.068 us; speedup vs baseline: 8.2169x; 1.1803x over previous
//
#include <hip/hip_runtime.h>
#include <hip/hip_bf16.h>
#include <math.h>

#define BS 16
#define C 192
#define H 120
#define W 120
#define HW 14400
#define AN 36
#define MID 18
#define CPG 64
#define EPS 1e-5f

typedef __attribute__((ext_vector_type(8))) short s16x8;
typedef __attribute__((ext_vector_type(4))) float f32x4;

static __device__ __forceinline__ short f2bf(float f) {
    union { float f; unsigned u; } v; v.f = f;
    unsigned r = (v.u + 0x7FFF + ((v.u >> 16) & 1)) >> 16;
    return (short)r;
}
static __device__ __forceinline__ s16x8 cvt8(float4 f0, float4 f1) {
    s16x8 v;
    v[0] = f2bf(f0.x); v[1] = f2bf(f0.y); v[2] = f2bf(f0.z); v[3] = f2bf(f0.w);
    v[4] = f2bf(f1.x); v[5] = f2bf(f1.y); v[6] = f2bf(f1.z); v[7] = f2bf(f1.w);
    return v;
}

// ---------------- pool6: x (b,c,120,120) -> P (b,c,36) ----------------
__global__ __launch_bounds__(256) void k_pool(const float* __restrict__ x,
                                              float* __restrict__ P) {
    int bc = blockIdx.x;
    const float* xp = x + (size_t)bc * HW;
    __shared__ float acc[AN];
    int tid = threadIdx.x;
    if (tid < AN) acc[tid] = 0.f;
    __syncthreads();
    for (int s = tid; s < 720; s += 256) {
        int y = s / 6, xs = s % 6;
        const float4* p4 = (const float4*)(xp + y * W + xs * 20);
        float sum = 0.f;
        #pragma unroll
        for (int i = 0; i < 5; ++i) {
            float4 v = p4[i];
            sum += v.x + v.y + v.z + v.w;
        }
        atomicAdd(&acc[(y / 20) * 6 + xs], sum);
    }
    __syncthreads();
    if (tid < AN) P[(size_t)bc * AN + tid] = acc[tid] * (1.f / 400.f);
}

// ---------------- v = val_w (192x192) * P (per b) ----------------
__global__ __launch_bounds__(256) void k_val(const float* __restrict__ valw,
                                             const float* __restrict__ P,
                                             float* __restrict__ V) {
    int b = blockIdx.x;
    __shared__ float Pl[C * AN];
    int tid = threadIdx.x;
    for (int i = tid; i < C * AN; i += 256) Pl[i] = P[(size_t)b * C * AN + i];
    __syncthreads();
    for (int o = tid; o < C * AN; o += 256) {
        int cc = o / AN, a = o % AN;
        float s = 0.f;
        for (int k = 0; k < C; ++k) s += valw[cc * C + k] * Pl[k * AN + a];
        V[(size_t)b * C * AN + o] = s;
    }
}

// ------------- grouped 3x3 conv + BN1 + ReLU via implicit-GEMM MFMA -------------
#define PXD 132
__global__ __launch_bounds__(256, 2) void k_conv_mfma(
        const float* __restrict__ x, const float* __restrict__ kw,
        const float* __restrict__ g1, const float* __restrict__ b1,
        const float* __restrict__ m1, const float* __restrict__ v1,
        float* __restrict__ k1) {
    int y = blockIdx.x, g = blockIdx.y, b = blockIdx.z;
    int t = threadIdx.x;
    __shared__ short xl[3 * PXD * 32];
    __shared__ short wl[9 * 64 * 32];

    int wv = t >> 6, l = t & 63;
    int lr = l & 15, hi = l >> 4;
    f32x4 acc[2][4];
    #pragma unroll
    for (int mt = 0; mt < 2; ++mt)
        #pragma unroll
        for (int nt = 0; nt < 4; ++nt)
            acc[mt][nt] = (f32x4){0.f, 0.f, 0.f, 0.f};

    int o = t & 3;
    int pxp = t >> 2;

    for (int cc = 0; cc < 2; ++cc) {
        int cc0 = cc * 32;
        #pragma unroll
        for (int r = 0; r < 3; ++r) {
            int yy = y + r - 1;
            bool rowok = (yy >= 0) && (yy < H);
            const float* xb = x + ((size_t)(b * C + g * CPG + cc0 + o * 8)) * HW + yy * W;
            #pragma unroll
            for (int pb = 0; pb < 3; ++pb) {
                int p = pxp + 64 * pb;
                if (p >= PXD) continue;
                int px = p - 1;
                s16x8 v = {0, 0, 0, 0, 0, 0, 0, 0};
                if (rowok && px >= 0 && px < W) {
                    #pragma unroll
                    for (int j = 0; j < 8; ++j) v[j] = f2bf(xb[(size_t)j * HW + px]);
                }
                *(s16x8*)&xl[((r * PXD) + p) * 32 + o * 8] = v;
            }
        }
        #pragma unroll
        for (int it = 0; it < 8; ++it) {
            int idx = t + 256 * it;
            int co = idx >> 5, ci = idx & 31;
            int cog = g * CPG + co;
            float inv = g1[cog] * rsqrtf(v1[cog] + EPS);
            const float* wp = kw + ((size_t)cog * CPG + cc0 + ci) * 9;
            #pragma unroll
            for (int tp = 0; tp < 9; ++tp)
                wl[(tp * 64 + co) * 32 + ci] = f2bf(wp[tp] * inv);
        }
        __syncthreads();
        #pragma unroll
        for (int tap = 0; tap < 9; ++tap) {
            int ky = tap / 3, kx = tap % 3;
            s16x8 B[4];
            #pragma unroll
            for (int nt = 0; nt < 4; ++nt)
                B[nt] = *(const s16x8*)&wl[(tap * 64 + nt * 16 + lr) * 32 + hi * 8];
            s16x8 A[2];
            #pragma unroll
            for (int mt = 0; mt < 2; ++mt) {
                int pp = (wv * 2 + mt) * 16 + kx + lr;
                A[mt] = *(const s16x8*)&xl[((ky * PXD) + pp) * 32 + hi * 8];
            }
            #pragma unroll
            for (int mt = 0; mt < 2; ++mt)
                #pragma unroll
                for (int nt = 0; nt < 4; ++nt)
                    acc[mt][nt] = __builtin_amdgcn_mfma_f32_16x16x32_bf16(
                        A[mt], B[nt], acc[mt][nt], 0, 0, 0);
        }
        __syncthreads();
    }
    #pragma unroll
    for (int nt = 0; nt < 4; ++nt) {
        int cog = g * CPG + nt * 16 + lr;
        float inv = g1[cog] * rsqrtf(v1[cog] + EPS);
        float beta = b1[cog] - m1[cog] * inv;
        #pragma unroll
        for (int mt = 0; mt < 2; ++mt) {
            int px = (wv * 2 + mt) * 16 + hi * 4;
            if (px > 116) continue;
            float* op = k1 + ((size_t)(b * C + cog)) * HW + y * W + px;
            float4 r;
            r.x = fmaxf(acc[mt][nt][0] + beta, 0.f);
            r.y = fmaxf(acc[mt][nt][1] + beta, 0.f);
            r.z = fmaxf(acc[mt][nt][2] + beta, 0.f);
            r.w = fmaxf(acc[mt][nt][3] + beta, 0.f);
            *(float4*)op = r;
        }
    }
}

// ------- scores via MFMA: S1[b,a,n] = agent·k1r, S2[b,a,n] = agent·q1 (raw logits) -------
#define SPX 128
#define BPS 200
__global__ __launch_bounds__(256, 3) void k_scores_mfma(
        const float* __restrict__ P, const float* __restrict__ k1,
        const float* __restrict__ x, float* __restrict__ S1,
        float* __restrict__ S2) {
    int b = blockIdx.y;
    int n0 = blockIdx.x * SPX;
    int t = threadIdx.x;
    int w = t >> 6, l = t & 63, lr = l & 15, hi = l >> 4;
    __shared__ short Bp[SPX * BPS];

    // preload agent A-fragments (rows 36..47 zero)
    s16x8 afr[3][6];
    const float* ab = P + (size_t)b * (C * AN);
    #pragma unroll
    for (int mt = 0; mt < 3; ++mt) {
        int row = mt * 16 + lr;
        #pragma unroll
        for (int kc = 0; kc < 6; ++kc) {
            s16x8 v = {0, 0, 0, 0, 0, 0, 0, 0};
            if (row < AN) {
                const float4* ap = (const float4*)(ab + row * C + kc * 32 + hi * 8);
                v = cvt8(ap[0], ap[1]);
            }
            afr[mt][kc] = v;
        }
    }

    const float* srcs[2] = {k1 + (size_t)b * C * HW + (size_t)n0 * C,
                            x + (size_t)b * C * HW + (size_t)n0 * C};
    float* dsts[2] = {S1, S2};
    #pragma unroll 1
    for (int s = 0; s < 2; ++s) {
        __syncthreads();
        const float4* src = (const float4*)srcs[s];
        for (int i = t; i < SPX * 24; i += 256) {
            int row = i / 24, c8 = (i % 24) * 8;
            s16x8 v = {0, 0, 0, 0, 0, 0, 0, 0};
            if (n0 + row < HW) v = cvt8(src[row * 48 + c8 / 4], src[row * 48 + c8 / 4 + 1]);
            *(s16x8*)&Bp[row * BPS + c8] = v;
        }
        __syncthreads();
        f32x4 acc[3][2];
        #pragma unroll
        for (int mt = 0; mt < 3; ++mt)
            #pragma unroll
            for (int pt = 0; pt < 2; ++pt)
                acc[mt][pt] = (f32x4){0.f, 0.f, 0.f, 0.f};
        #pragma unroll
        for (int kc = 0; kc < 6; ++kc) {
            s16x8 bf[2];
            #pragma unroll
            for (int pt = 0; pt < 2; ++pt) {
                int px = (w * 2 + pt) * 16 + lr;
                bf[pt] = *(const s16x8*)&Bp[px * BPS + kc * 32 + hi * 8];
            }
            #pragma unroll
            for (int mt = 0; mt < 3; ++mt)
                #pragma unroll
                for (int pt = 0; pt < 2; ++pt)
                    acc[mt][pt] = __builtin_amdgcn_mfma_f32_16x16x32_bf16(
                        afr[mt][kc], bf[pt], acc[mt][pt], 0, 0, 0);
        }
        float* dst = dsts[s] + (size_t)b * AN * HW + n0;
        #pragma unroll
        for (int mt = 0; mt < 3; ++mt)
            #pragma unroll
            for (int pt = 0; pt < 2; ++pt) {
                int px = (w * 2 + pt) * 16 + lr;
                if (n0 + px >= HW) continue;
                #pragma unroll
                for (int r = 0; r < 4; ++r) {
                    int a = mt * 16 + hi * 4 + r;
                    if (a < AN) dst[(size_t)a * HW + px] = acc[mt][pt][r];
                }
            }
    }
}

// ---------------- per-row (b,a) stats of S1: max and 1/sum(exp) ----------------
__global__ __launch_bounds__(256) void k_rowstats(const float* __restrict__ S,
                                                  float* __restrict__ stats) {
    int row = blockIdx.x;           // 0..575
    const float* p = S + (size_t)row * HW;
    int tid = threadIdx.x;
    __shared__ float red[4];
    float m = -1e30f;
    for (int i = tid; i < HW / 4; i += 256) {
        float4 v = ((const float4*)p)[i];
        m = fmaxf(m, fmaxf(fmaxf(v.x, v.y), fmaxf(v.z, v.w)));
    }
    #pragma unroll
    for (int off = 32; off > 0; off >>= 1) m = fmaxf(m, __shfl_down(m, off, 64));
    if ((tid & 63) == 0) red[tid >> 6] = m;
    __syncthreads();
    m = fmaxf(fmaxf(red[0], red[1]), fmaxf(red[2], red[3]));
    __syncthreads();
    float s = 0.f;
    for (int i = tid; i < HW / 4; i += 256) {
        float4 v = ((const float4*)p)[i];
        s += __expf(v.x - m) + __expf(v.y - m) + __expf(v.z - m) + __expf(v.w - m);
    }
    #pragma unroll
    for (int off = 32; off > 0; off >>= 1) s += __shfl_down(s, off, 64);
    if ((tid & 63) == 0) red[tid >> 6] = s;
    __syncthreads();
    if (tid == 0) {
        stats[row] = m;
        stats[576 + row] = 1.f / (red[0] + red[1] + red[2] + red[3]);
    }
}

// ------- fused: softmax(S1) via stats, softmax36(S2), conv1+BN2+ReLU, conv2(mean-folded) -------
__global__ __launch_bounds__(256) void k_fuse(const float* __restrict__ A1,
                                              const float* __restrict__ stats,
                                              const float* __restrict__ S2,
                                              const float* __restrict__ w1,
                                              const float* __restrict__ g2,
                                              const float* __restrict__ b2,
                                              const float* __restrict__ m2,
                                              const float* __restrict__ v2,
                                              const float* __restrict__ w2,
                                              const float* __restrict__ bias2,
                                              float* __restrict__ AM) {
    int b = blockIdx.y;
    int tid = threadIdx.x;
    int N = blockIdx.x * 256 + tid;
    __shared__ float W1f[MID * 72];
    __shared__ float b1f[MID];
    __shared__ float W2m[AN * MID];
    __shared__ float b2m[AN];
    __shared__ float sm_m[AN], sm_ri[AN];
    for (int i = tid; i < MID * 72; i += 256) {
        int m = i / 72;
        W1f[i] = w1[i] * (g2[m] * rsqrtf(v2[m] + EPS));
    }
    if (tid < MID) {
        float inv = g2[tid] * rsqrtf(v2[tid] + EPS);
        b1f[tid] = b2[tid] - m2[tid] * inv;
    }
    for (int i = tid; i < AN * MID; i += 256) {
        int a = i / MID, m = i % MID;
        float s = 0.f;
        #pragma unroll
        for (int k = 0; k < 9; ++k) s += w2[(a * 9 + k) * MID + m];
        W2m[i] = s * (1.f / 9.f);
    }
    if (tid < AN) {
        float s = 0.f;
        #pragma unroll
        for (int k = 0; k < 9; ++k) s += bias2[tid * 9 + k];
        b2m[tid] = s * (1.f / 9.f);
        sm_m[tid] = stats[b * AN + tid];
        sm_ri[tid] = stats[576 + b * AN + tid];
    }
    __syncthreads();
    if (N >= HW) return;
    float yv[72];
    const float* a1p = A1 + (size_t)b * AN * HW + N;
    #pragma unroll
    for (int j = 0; j < AN; ++j)
        yv[j] = __expf(a1p[(size_t)j * HW] - sm_m[j]) * sm_ri[j];
    const float* s2p = S2 + (size_t)b * AN * HW + N;
    float mx = -1e30f;
    #pragma unroll
    for (int j = 0; j < AN; ++j) {
        float v = s2p[(size_t)j * HW];
        yv[AN + j] = v;
        mx = fmaxf(mx, v);
    }
    float ssum = 0.f;
    #pragma unroll
    for (int j = 0; j < AN; ++j) {
        float e = __expf(yv[AN + j] - mx);
        yv[AN + j] = e;
        ssum += e;
    }
    float rs = 1.f / ssum;
    #pragma unroll
    for (int j = 0; j < AN; ++j) yv[AN + j] *= rs;
    float t[MID];
    #pragma unroll
    for (int m = 0; m < MID; ++m) {
        float a = b1f[m];
        #pragma unroll
        for (int j = 0; j < 72; ++j) a += W1f[m * 72 + j] * yv[j];
        t[m] = a > 0.f ? a : 0.f;
    }
    float* amp = AM + (size_t)b * AN * HW + N;
    #pragma unroll
    for (int a = 0; a < AN; ++a) {
        float acc = b2m[a];
        #pragma unroll
        for (int m = 0; m < MID; ++m) acc += W2m[a * MID + m] * t[m];
        amp[(size_t)a * HW] = acc;
    }
}

// ------- out[b,cc,n] = sum_a softmax36(att window)[a]*v[b,cc,a] + k1[b,cc,n] -------
__global__ __launch_bounds__(256) void k_out(const float* __restrict__ AM,
                                             const float* __restrict__ V,
                                             float* __restrict__ k1out) {
    int b = blockIdx.y;
    int tid = threadIdx.x;
    int N = blockIdx.x * 256 + tid;
    __shared__ float Vl[C * AN];
    for (int i = tid; i < C * AN; i += 256) Vl[i] = V[(size_t)b * C * AN + i];
    __syncthreads();
    if (N >= HW) return;
    int a = N / 400;
    int n0 = (N % 400) * AN;
    const float4* amr = (const float4*)(AM + ((size_t)b * AN + a) * HW + n0);
    float w[AN];
    float mx = -1e30f;
    #pragma unroll
    for (int i4 = 0; i4 < 9; ++i4) {
        float4 q = amr[i4];
        w[i4 * 4 + 0] = q.x; w[i4 * 4 + 1] = q.y;
        w[i4 * 4 + 2] = q.z; w[i4 * 4 + 3] = q.w;
    }
    #pragma unroll
    for (int i = 0; i < AN; ++i) mx = fmaxf(mx, w[i]);
    float s = 0.f;
    #pragma unroll
    for (int i = 0; i < AN; ++i) { w[i] = __expf(w[i] - mx); s += w[i]; }
    float rs = 1.f / s;
    #pragma unroll
    for (int i = 0; i < AN; ++i) w[i] *= rs;
    float* op = k1out + (size_t)b * C * HW + N;
    for (int cc = 0; cc < C; ++cc) {
        float acc = op[(size_t)cc * HW];
        const float* vr = Vl + cc * AN;
        #pragma unroll
        for (int i = 0; i < AN; ++i) acc += w[i] * vr[i];
        op[(size_t)cc * HW] = acc;
    }
}

extern "C" void kernel_launch(void* const* d_in, const int* in_sizes, int n_in,
                              void* d_out, int out_size, void* d_ws, size_t ws_size,
                              hipStream_t stream) {
    const float* x      = (const float*)d_in[0];
    const float* key_w  = (const float*)d_in[1];
    const float* bn1_g  = (const float*)d_in[2];
    const float* bn1_b  = (const float*)d_in[3];
    const float* bn1_m  = (const float*)d_in[4];
    const float* bn1_v  = (const float*)d_in[5];
    const float* val_w  = (const float*)d_in[6];
    const float* att_w1 = (const float*)d_in[7];
    const float* bn2_g  = (const float*)d_in[8];
    const float* bn2_b  = (const float*)d_in[9];
    const float* bn2_m  = (const float*)d_in[10];
    const float* bn2_v  = (const float*)d_in[11];
    const float* att_w2 = (const float*)d_in[12];
    const float* att_b2 = (const float*)d_in[13];
    float* out = (float*)d_out;                 // also holds k1
    float* ws  = (float*)d_ws;

    float* P  = ws;
    float* V  = P + (size_t)BS * C * AN;
    float* S1 = V + (size_t)BS * C * AN;
    float* S2 = S1 + (size_t)BS * AN * HW;
    float* AM = S2 + (size_t)BS * AN * HW;
    float* ST = AM + (size_t)BS * AN * HW;      // 2*576 floats

    k_pool<<<BS * C, 256, 0, stream>>>(x, P);
    k_val<<<BS, 256, 0, stream>>>(val_w, P, V);
    k_conv_mfma<<<dim3(H, 3, BS), 256, 0, stream>>>(x, key_w, bn1_g, bn1_b, bn1_m, bn1_v, out);
    k_scores_mfma<<<dim3((HW + SPX - 1) / SPX, BS), 256, 0, stream>>>(P, out, x, S1, S2);
    k_rowstats<<<BS * AN, 256, 0, stream>>>(S1, ST);
    k_fuse<<<dim3((HW + 255) / 256, BS), 256, 0, stream>>>(
        S1, ST, S2, att_w1, bn2_g, bn2_b, bn2_m, bn2_v, att_w2, att_b2, AM);
    k_out<<<dim3((HW + 255) / 256, BS), 256, 0, stream>>>(AM, V, out);
}

// Round 4
// 652.724 us; speedup vs baseline: 8.3345x; 1.0143x over previous
//
#include <hip/hip_runtime.h>
#include <hip/hip_bf16.h>
#include <math.h>

#define BS 16
#define C 192
#define H 120
#define W 120
#define HW 14400
#define AN 36
#define MID 18
#define CPG 64
#define EPS 1e-5f
#define PXD 132
#define SPX 128
#define BPS 200

typedef __attribute__((ext_vector_type(8))) short s16x8;
typedef __attribute__((ext_vector_type(4))) float f32x4;
typedef __attribute__((ext_vector_type(4))) unsigned short u16x4;

static __device__ __forceinline__ short f2bf(float f) {
    union { float f; unsigned u; } v; v.f = f;
    unsigned r = (v.u + 0x7FFF + ((v.u >> 16) & 1)) >> 16;
    return (short)r;
}
static __device__ __forceinline__ float bf2f(unsigned short u) {
    union { unsigned u; float f; } v; v.u = ((unsigned)u) << 16;
    return v.f;
}
static __device__ __forceinline__ s16x8 cvt8(float4 f0, float4 f1) {
    s16x8 v;
    v[0] = f2bf(f0.x); v[1] = f2bf(f0.y); v[2] = f2bf(f0.z); v[3] = f2bf(f0.w);
    v[4] = f2bf(f1.x); v[5] = f2bf(f1.y); v[6] = f2bf(f1.z); v[7] = f2bf(f1.w);
    return v;
}

// ---------------- xT: x f32 [b,c,hw] -> bf16 [b,hw,c] (LDS-tiled transpose) ----------------
__global__ __launch_bounds__(256) void k_xt(const float* __restrict__ x,
                                            unsigned short* __restrict__ xT) {
    int b = blockIdx.y;
    int n0 = blockIdx.x * SPX;
    int t = threadIdx.x;
    __shared__ unsigned short L[SPX * BPS];
    // phase 1: px fastest -> coalesced f32 reads, gather 8 ch per unit
    for (int u = t; u < SPX * 24; u += 256) {
        int px = u & (SPX - 1);
        int oc = u >> 7;                 // 0..23
        int n = n0 + px;
        s16x8 v = {0, 0, 0, 0, 0, 0, 0, 0};
        if (n < HW) {
            const float* xp = x + ((size_t)b * C + oc * 8) * HW + n;
            #pragma unroll
            for (int j = 0; j < 8; ++j) v[j] = f2bf(xp[(size_t)j * HW]);
        }
        *(s16x8*)&L[px * BPS + oc * 8] = v;
    }
    __syncthreads();
    // phase 2: oc fastest -> coalesced bf16 row stores
    for (int u = t; u < SPX * 24; u += 256) {
        int row = u / 24, oc = u - row * 24;
        int n = n0 + row;
        if (n < HW)
            *(s16x8*)&xT[((size_t)b * HW + n) * C + oc * 8] =
                *(s16x8*)&L[row * BPS + oc * 8];
    }
}

// ---------------- pool6: x (b,c,120,120) -> P (b,c,36) ----------------
__global__ __launch_bounds__(256) void k_pool(const float* __restrict__ x,
                                              float* __restrict__ P) {
    int bc = blockIdx.x;
    const float* xp = x + (size_t)bc * HW;
    __shared__ float acc[AN];
    int tid = threadIdx.x;
    if (tid < AN) acc[tid] = 0.f;
    __syncthreads();
    for (int s = tid; s < 720; s += 256) {
        int y = s / 6, xs = s % 6;
        const float4* p4 = (const float4*)(xp + y * W + xs * 20);
        float sum = 0.f;
        #pragma unroll
        for (int i = 0; i < 5; ++i) {
            float4 v = p4[i];
            sum += v.x + v.y + v.z + v.w;
        }
        atomicAdd(&acc[(y / 20) * 6 + xs], sum);
    }
    __syncthreads();
    if (tid < AN) P[(size_t)bc * AN + tid] = acc[tid] * (1.f / 400.f);
}

// ---------------- v = val_w (192x192) * P (per b) ----------------
__global__ __launch_bounds__(256) void k_val(const float* __restrict__ valw,
                                             const float* __restrict__ P,
                                             float* __restrict__ V) {
    int b = blockIdx.x;
    __shared__ float Pl[C * AN];
    int tid = threadIdx.x;
    for (int i = tid; i < C * AN; i += 256) Pl[i] = P[(size_t)b * C * AN + i];
    __syncthreads();
    for (int o = tid; o < C * AN; o += 256) {
        int cc = o / AN, a = o % AN;
        float s = 0.f;
        for (int k = 0; k < C; ++k) s += valw[cc * C + k] * Pl[k * AN + a];
        V[(size_t)b * C * AN + o] = s;
    }
}

// ------------- grouped 3x3 conv + BN1 + ReLU, implicit-GEMM MFMA, conflict-free LDS -------------
// block = (y, group, batch); tile 128 px x 64 co; waves 2x2 (wm px-half, wn co-half).
// xl unit(o,r,p) = (o*3+r)*PXD+p : 8 consecutive ci (bf16) at one padded px.
// wl unit(tap,hi,co) = (tap*4+hi)*64+co : 8 ci at one co, BN-scaled.
__global__ __launch_bounds__(256, 2) void k_conv_mfma(
        const unsigned short* __restrict__ xT, const float* __restrict__ kw,
        const float* __restrict__ g1, const float* __restrict__ b1,
        const float* __restrict__ m1, const float* __restrict__ v1,
        float* __restrict__ k1f, unsigned short* __restrict__ k1b, int writeF32) {
    int y = blockIdx.x, g = blockIdx.y, b = blockIdx.z;
    int t = threadIdx.x;
    __shared__ short xl[4 * 3 * PXD * 8];    // 25,344 B
    __shared__ short wl[9 * 4 * 64 * 8];     // 36,864 B

    int w = t >> 6, l = t & 63, lr = l & 15, hi = l >> 4;
    int wm = w & 1, wn = w >> 1;
    f32x4 acc[4][2];
    #pragma unroll
    for (int mt = 0; mt < 4; ++mt)
        #pragma unroll
        for (int nt = 0; nt < 2; ++nt)
            acc[mt][nt] = (f32x4){0.f, 0.f, 0.f, 0.f};

    for (int cc = 0; cc < 2; ++cc) {
        int cc0 = cc * 32;
        // stage x: 1584 short8 copies from xT
        for (int u = t; u < 1584; u += 256) {
            int o = u & 3, rp = u >> 2;
            int r = rp / PXD, p = rp - r * PXD;
            int yy = y + r - 1;
            int px = p - 1;
            s16x8 v = {0, 0, 0, 0, 0, 0, 0, 0};
            if (yy >= 0 && yy < H && px >= 0 && px < W)
                v = *(const s16x8*)&xT[(((size_t)b * HW) + yy * W + px) * C +
                                       g * CPG + cc0 + o * 8];
            *(s16x8*)&xl[((o * 3 + r) * PXD + p) * 8] = v;
        }
        // stage w: BN-folded bf16
        #pragma unroll
        for (int it = 0; it < 8; ++it) {
            int idx = t + 256 * it;                // 0..2047
            int co = idx >> 5, ci = idx & 31;
            int hh = ci >> 3, e = ci & 7;
            int cog = g * CPG + co;
            float inv = g1[cog] * rsqrtf(v1[cog] + EPS);
            const float* wp = kw + ((size_t)cog * CPG + cc0 + ci) * 9;
            #pragma unroll
            for (int tp = 0; tp < 9; ++tp)
                wl[((tp * 4 + hh) * 64 + co) * 8 + e] = f2bf(wp[tp] * inv);
        }
        __syncthreads();
        #pragma unroll
        for (int tap = 0; tap < 9; ++tap) {
            int ky = tap / 3, kx = tap % 3;
            s16x8 B[2];
            #pragma unroll
            for (int nt = 0; nt < 2; ++nt)
                B[nt] = *(const s16x8*)&wl[((tap * 4 + hi) * 64 +
                                            (wn * 2 + nt) * 16 + lr) * 8];
            s16x8 A[4];
            #pragma unroll
            for (int mt = 0; mt < 4; ++mt) {
                int p = (wm * 4 + mt) * 16 + lr + kx;
                A[mt] = *(const s16x8*)&xl[((hi * 3 + ky) * PXD + p) * 8];
            }
            #pragma unroll
            for (int mt = 0; mt < 4; ++mt)
                #pragma unroll
                for (int nt = 0; nt < 2; ++nt)
                    acc[mt][nt] = __builtin_amdgcn_mfma_f32_16x16x32_bf16(
                        A[mt], B[nt], acc[mt][nt], 0, 0, 0);
        }
        __syncthreads();
    }
    // epilogue: +beta, ReLU, store f32 (tier B) or bf16 (tier A)
    #pragma unroll
    for (int nt = 0; nt < 2; ++nt) {
        int cog = g * CPG + (wn * 2 + nt) * 16 + lr;
        float inv = g1[cog] * rsqrtf(v1[cog] + EPS);
        float beta = b1[cog] - m1[cog] * inv;
        #pragma unroll
        for (int mt = 0; mt < 4; ++mt) {
            int px0 = (wm * 4 + mt) * 16 + hi * 4;
            if (px0 > 116) continue;
            float r0 = fmaxf(acc[mt][nt][0] + beta, 0.f);
            float r1 = fmaxf(acc[mt][nt][1] + beta, 0.f);
            float r2 = fmaxf(acc[mt][nt][2] + beta, 0.f);
            float r3 = fmaxf(acc[mt][nt][3] + beta, 0.f);
            size_t base = ((size_t)(b * C + cog)) * HW + y * W + px0;
            if (writeF32) {
                *(float4*)&k1f[base] = make_float4(r0, r1, r2, r3);
            } else {
                u16x4 q;
                q[0] = (unsigned short)f2bf(r0); q[1] = (unsigned short)f2bf(r1);
                q[2] = (unsigned short)f2bf(r2); q[3] = (unsigned short)f2bf(r3);
                *(u16x4*)&k1b[base] = q;
            }
        }
    }
}

// ------- scores via MFMA: S1[b,a,n] = agent . k1view, S2 = agent . xview (raw logits) -------
__global__ __launch_bounds__(256, 3) void k_scores_mfma(
        const float* __restrict__ Pp, const float* __restrict__ k1f,
        const unsigned short* __restrict__ k1b, const float* __restrict__ x,
        float* __restrict__ S1, float* __restrict__ S2) {
    int b = blockIdx.y;
    int n0 = blockIdx.x * SPX;
    int t = threadIdx.x;
    int w = t >> 6, l = t & 63, lr = l & 15, hi = l >> 4;
    __shared__ short Bp[SPX * BPS];

    // agent A-fragments (rows 36..47 zero)
    s16x8 afr[3][6];
    const float* ab = Pp + (size_t)b * (C * AN);
    #pragma unroll
    for (int mt = 0; mt < 3; ++mt) {
        int row = mt * 16 + lr;
        #pragma unroll
        for (int kc = 0; kc < 6; ++kc) {
            s16x8 v = {0, 0, 0, 0, 0, 0, 0, 0};
            if (row < AN) {
                const float4* ap = (const float4*)(ab + row * C + kc * 32 + hi * 8);
                v = cvt8(ap[0], ap[1]);
            }
            afr[mt][kc] = v;
        }
    }

    #pragma unroll 1
    for (int s = 0; s < 2; ++s) {
        __syncthreads();
        if (s == 0 && k1b) {
            const unsigned short* src = k1b + (size_t)b * C * HW + (size_t)n0 * C;
            for (int i = t; i < SPX * 24; i += 256) {
                int row = i / 24, o = i - row * 24;
                s16x8 v = {0, 0, 0, 0, 0, 0, 0, 0};
                if (n0 + row < HW) v = *(const s16x8*)&src[row * C + o * 8];
                *(s16x8*)&Bp[row * BPS + o * 8] = v;
            }
        } else {
            const float* sf = (s == 0) ? k1f : x;
            const float4* src = (const float4*)(sf + (size_t)b * C * HW + (size_t)n0 * C);
            for (int i = t; i < SPX * 24; i += 256) {
                int row = i / 24, c8 = (i - row * 24) * 8;
                s16x8 v = {0, 0, 0, 0, 0, 0, 0, 0};
                if (n0 + row < HW)
                    v = cvt8(src[row * 48 + c8 / 4], src[row * 48 + c8 / 4 + 1]);
                *(s16x8*)&Bp[row * BPS + c8] = v;
            }
        }
        __syncthreads();
        f32x4 acc[3][2];
        #pragma unroll
        for (int mt = 0; mt < 3; ++mt)
            #pragma unroll
            for (int pt = 0; pt < 2; ++pt)
                acc[mt][pt] = (f32x4){0.f, 0.f, 0.f, 0.f};
        #pragma unroll
        for (int kc = 0; kc < 6; ++kc) {
            s16x8 bf[2];
            #pragma unroll
            for (int pt = 0; pt < 2; ++pt) {
                int px = (w * 2 + pt) * 16 + lr;
                bf[pt] = *(const s16x8*)&Bp[px * BPS + kc * 32 + hi * 8];
            }
            #pragma unroll
            for (int mt = 0; mt < 3; ++mt)
                #pragma unroll
                for (int pt = 0; pt < 2; ++pt)
                    acc[mt][pt] = __builtin_amdgcn_mfma_f32_16x16x32_bf16(
                        afr[mt][kc], bf[pt], acc[mt][pt], 0, 0, 0);
        }
        float* dst = (s == 0 ? S1 : S2) + (size_t)b * AN * HW + n0;
        #pragma unroll
        for (int mt = 0; mt < 3; ++mt)
            #pragma unroll
            for (int pt = 0; pt < 2; ++pt) {
                int px = (w * 2 + pt) * 16 + lr;
                if (n0 + px >= HW) continue;
                #pragma unroll
                for (int r = 0; r < 4; ++r) {
                    int a = mt * 16 + hi * 4 + r;
                    if (a < AN) dst[(size_t)a * HW + px] = acc[mt][pt][r];
                }
            }
    }
}

// ---------------- per-row (b,a) stats of S1: max and 1/sum(exp) ----------------
__global__ __launch_bounds__(256) void k_rowstats(const float* __restrict__ S,
                                                  float* __restrict__ stats) {
    int row = blockIdx.x;
    const float* p = S + (size_t)row * HW;
    int tid = threadIdx.x;
    __shared__ float red[4];
    float m = -1e30f;
    for (int i = tid; i < HW / 4; i += 256) {
        float4 v = ((const float4*)p)[i];
        m = fmaxf(m, fmaxf(fmaxf(v.x, v.y), fmaxf(v.z, v.w)));
    }
    #pragma unroll
    for (int off = 32; off > 0; off >>= 1) m = fmaxf(m, __shfl_down(m, off, 64));
    if ((tid & 63) == 0) red[tid >> 6] = m;
    __syncthreads();
    m = fmaxf(fmaxf(red[0], red[1]), fmaxf(red[2], red[3]));
    __syncthreads();
    float s = 0.f;
    for (int i = tid; i < HW / 4; i += 256) {
        float4 v = ((const float4*)p)[i];
        s += __expf(v.x - m) + __expf(v.y - m) + __expf(v.z - m) + __expf(v.w - m);
    }
    #pragma unroll
    for (int off = 32; off > 0; off >>= 1) s += __shfl_down(s, off, 64);
    if ((tid & 63) == 0) red[tid >> 6] = s;
    __syncthreads();
    if (tid == 0) {
        stats[row] = m;
        stats[576 + row] = 1.f / (red[0] + red[1] + red[2] + red[3]);
    }
}

// ------- fused: softmax(S1) via stats, softmax36(S2), conv1+BN2+ReLU, conv2(mean-folded) -------
__global__ __launch_bounds__(256) void k_fuse(const float* __restrict__ A1,
                                              const float* __restrict__ stats,
                                              const float* __restrict__ S2,
                                              const float* __restrict__ w1,
                                              const float* __restrict__ g2,
                                              const float* __restrict__ b2,
                                              const float* __restrict__ m2,
                                              const float* __restrict__ v2,
                                              const float* __restrict__ w2,
                                              const float* __restrict__ bias2,
                                              float* __restrict__ AM) {
    int b = blockIdx.y;
    int tid = threadIdx.x;
    int N = blockIdx.x * 256 + tid;
    __shared__ float W1f[MID * 72];
    __shared__ float b1f[MID];
    __shared__ float W2m[AN * MID];
    __shared__ float b2m[AN];
    __shared__ float sm_m[AN], sm_ri[AN];
    for (int i = tid; i < MID * 72; i += 256) {
        int m = i / 72;
        W1f[i] = w1[i] * (g2[m] * rsqrtf(v2[m] + EPS));
    }
    if (tid < MID) {
        float inv = g2[tid] * rsqrtf(v2[tid] + EPS);
        b1f[tid] = b2[tid] - m2[tid] * inv;
    }
    for (int i = tid; i < AN * MID; i += 256) {
        int a = i / MID, m = i % MID;
        float s = 0.f;
        #pragma unroll
        for (int k = 0; k < 9; ++k) s += w2[(a * 9 + k) * MID + m];
        W2m[i] = s * (1.f / 9.f);
    }
    if (tid < AN) {
        float s = 0.f;
        #pragma unroll
        for (int k = 0; k < 9; ++k) s += bias2[tid * 9 + k];
        b2m[tid] = s * (1.f / 9.f);
        sm_m[tid] = stats[b * AN + tid];
        sm_ri[tid] = stats[576 + b * AN + tid];
    }
    __syncthreads();
    if (N >= HW) return;
    float yv[72];
    const float* a1p = A1 + (size_t)b * AN * HW + N;
    #pragma unroll
    for (int j = 0; j < AN; ++j)
        yv[j] = __expf(a1p[(size_t)j * HW] - sm_m[j]) * sm_ri[j];
    const float* s2p = S2 + (size_t)b * AN * HW + N;
    float mx = -1e30f;
    #pragma unroll
    for (int j = 0; j < AN; ++j) {
        float v = s2p[(size_t)j * HW];
        yv[AN + j] = v;
        mx = fmaxf(mx, v);
    }
    float ssum = 0.f;
    #pragma unroll
    for (int j = 0; j < AN; ++j) {
        float e = __expf(yv[AN + j] - mx);
        yv[AN + j] = e;
        ssum += e;
    }
    float rs = 1.f / ssum;
    #pragma unroll
    for (int j = 0; j < AN; ++j) yv[AN + j] *= rs;
    float t[MID];
    #pragma unroll
    for (int m = 0; m < MID; ++m) {
        float a = b1f[m];
        #pragma unroll
        for (int j = 0; j < 72; ++j) a += W1f[m * 72 + j] * yv[j];
        t[m] = a > 0.f ? a : 0.f;
    }
    float* amp = AM + (size_t)b * AN * HW + N;
    #pragma unroll
    for (int a = 0; a < AN; ++a) {
        float acc = b2m[a];
        #pragma unroll
        for (int m = 0; m < MID; ++m) acc += W2m[a * MID + m] * t[m];
        amp[(size_t)a * HW] = acc;
    }
}

// ------- out[b,cc,n] = sum_a softmax36(att window)[a]*v[b,cc,a] + k1[b,cc,n] -------
__global__ __launch_bounds__(256) void k_out(const float* __restrict__ AM,
                                             const float* __restrict__ V,
                                             const unsigned short* __restrict__ k1b,
                                             float* __restrict__ outp) {
    int b = blockIdx.y;
    int tid = threadIdx.x;
    int N = blockIdx.x * 256 + tid;
    __shared__ float Vl[C * AN];
    for (int i = tid; i < C * AN; i += 256) Vl[i] = V[(size_t)b * C * AN + i];
    __syncthreads();
    if (N >= HW) return;
    int a = N / 400;
    int n0 = (N % 400) * AN;
    const float4* amr = (const float4*)(AM + ((size_t)b * AN + a) * HW + n0);
    float wv[AN];
    float mx = -1e30f;
    #pragma unroll
    for (int i4 = 0; i4 < 9; ++i4) {
        float4 q = amr[i4];
        wv[i4 * 4 + 0] = q.x; wv[i4 * 4 + 1] = q.y;
        wv[i4 * 4 + 2] = q.z; wv[i4 * 4 + 3] = q.w;
    }
    #pragma unroll
    for (int i = 0; i < AN; ++i) mx = fmaxf(mx, wv[i]);
    float s = 0.f;
    #pragma unroll
    for (int i = 0; i < AN; ++i) { wv[i] = __expf(wv[i] - mx); s += wv[i]; }
    float rs = 1.f / s;
    #pragma unroll
    for (int i = 0; i < AN; ++i) wv[i] *= rs;
    float* op = outp + (size_t)b * C * HW + N;
    if (k1b) {
        const unsigned short* kp = k1b + (size_t)b * C * HW + N;
        for (int cc = 0; cc < C; ++cc) {
            float acc = bf2f(kp[(size_t)cc * HW]);
            const float* vr = Vl + cc * AN;
            #pragma unroll
            for (int i = 0; i < AN; ++i) acc += wv[i] * vr[i];
            op[(size_t)cc * HW] = acc;
        }
    } else {
        for (int cc = 0; cc < C; ++cc) {
            float acc = op[(size_t)cc * HW];
            const float* vr = Vl + cc * AN;
            #pragma unroll
            for (int i = 0; i < AN; ++i) acc += wv[i] * vr[i];
            op[(size_t)cc * HW] = acc;
        }
    }
}

extern "C" void kernel_launch(void* const* d_in, const int* in_sizes, int n_in,
                              void* d_out, int out_size, void* d_ws, size_t ws_size,
                              hipStream_t stream) {
    const float* x      = (const float*)d_in[0];
    const float* key_w  = (const float*)d_in[1];
    const float* bn1_g  = (const float*)d_in[2];
    const float* bn1_b  = (const float*)d_in[3];
    const float* bn1_m  = (const float*)d_in[4];
    const float* bn1_v  = (const float*)d_in[5];
    const float* val_w  = (const float*)d_in[6];
    const float* att_w1 = (const float*)d_in[7];
    const float* bn2_g  = (const float*)d_in[8];
    const float* bn2_b  = (const float*)d_in[9];
    const float* bn2_m  = (const float*)d_in[10];
    const float* bn2_v  = (const float*)d_in[11];
    const float* att_w2 = (const float*)d_in[12];
    const float* att_b2 = (const float*)d_in[13];
    float* out = (float*)d_out;
    float* ws  = (float*)d_ws;

    size_t nP = (size_t)BS * C * AN;      // 110592
    size_t nS = (size_t)BS * AN * HW;     // 8294400
    float* P  = ws;
    float* V  = P + nP;
    float* ST = V + nP;                   // 1152 floats
    float* S1 = ST + 1152;
    float* S2 = S1 + nS;
    float* AM = S2 + nS;
    // xT (bf16, 88.5 MB) aliases S1+S2+part of AM: lifetime [k_xt .. k_conv] only.
    unsigned short* xT = (unsigned short*)S1;
    // tier A: bf16 k1 after AM if workspace allows (lifetime [k_conv .. k_out]).
    size_t baseBytes = (nP * 2 + 1152 + 3 * nS) * sizeof(float);
    size_t k1bBytes  = (size_t)BS * C * HW * sizeof(unsigned short);
    unsigned short* k1b = (ws_size >= baseBytes + k1bBytes)
                              ? (unsigned short*)(AM + nS) : nullptr;
    int writeF32 = (k1b == nullptr) ? 1 : 0;

    k_xt<<<dim3((HW + SPX - 1) / SPX, BS), 256, 0, stream>>>(x, xT);
    k_pool<<<BS * C, 256, 0, stream>>>(x, P);
    k_val<<<BS, 256, 0, stream>>>(val_w, P, V);
    k_conv_mfma<<<dim3(H, 3, BS), 256, 0, stream>>>(
        xT, key_w, bn1_g, bn1_b, bn1_m, bn1_v, out, k1b, writeF32);
    k_scores_mfma<<<dim3((HW + SPX - 1) / SPX, BS), 256, 0, stream>>>(
        P, out, k1b, x, S1, S2);
    k_rowstats<<<BS * AN, 256, 0, stream>>>(S1, ST);
    k_fuse<<<dim3((HW + 255) / 256, BS), 256, 0, stream>>>(
        S1, ST, S2, att_w1, bn2_g, bn2_b, bn2_m, bn2_v, att_w2, att_b2, AM);
    k_out<<<dim3((HW + 255) / 256, BS), 256, 0, stream>>>(AM, V, k1b, out);
}

// Round 5
// 623.730 us; speedup vs baseline: 8.7220x; 1.0465x over previous
//
#include <hip/hip_runtime.h>
#include <hip/hip_bf16.h>
#include <math.h>

#define BS 16
#define C 192
#define H 120
#define W 120
#define HW 14400
#define AN 36
#define MID 18
#define CPG 64
#define EPS 1e-5f
#define SPX 128
#define BPS 200
#define XLD 133   // padded px stride in conv LDS (units)
#define WLD 65    // padded co stride in conv LDS (units)
#define NWU 14040 // 3 g * 2 cc * 9 tap * 4 hi * 65

typedef __attribute__((ext_vector_type(8))) short s16x8;
typedef __attribute__((ext_vector_type(4))) float f32x4;
typedef __attribute__((ext_vector_type(4))) unsigned short u16x4;

static __device__ __forceinline__ short f2bf(float f) {
    union { float f; unsigned u; } v; v.f = f;
    unsigned r = (v.u + 0x7FFF + ((v.u >> 16) & 1)) >> 16;
    return (short)r;
}
static __device__ __forceinline__ float bf2f(unsigned short u) {
    union { unsigned u; float f; } v; v.u = ((unsigned)u) << 16;
    return v.f;
}
static __device__ __forceinline__ s16x8 cvt8(float4 f0, float4 f1) {
    s16x8 v;
    v[0] = f2bf(f0.x); v[1] = f2bf(f0.y); v[2] = f2bf(f0.z); v[3] = f2bf(f0.w);
    v[4] = f2bf(f1.x); v[5] = f2bf(f1.y); v[6] = f2bf(f1.z); v[7] = f2bf(f1.w);
    return v;
}

// ------- fold BN1 into key_w, bf16, conv-LDS layout: [g][cc][(tap*4+hi)*65+co][8e] -------
__global__ __launch_bounds__(256) void k_wfold(const float* __restrict__ kw,
                                               const float* __restrict__ g1,
                                               const float* __restrict__ v1,
                                               unsigned short* __restrict__ Wb) {
    int u = blockIdx.x * 256 + threadIdx.x;
    if (u >= NWU) return;
    int gc = u / 2340, rem = u - gc * 2340;   // 2340 = 9*4*65
    int g = gc >> 1, cc = gc & 1;
    int th = rem / WLD, co = rem - th * WLD;
    int tap = th >> 2, hi = th & 3;
    s16x8 v = {0, 0, 0, 0, 0, 0, 0, 0};
    if (co < 64) {
        int cog = g * 64 + co;
        float inv = g1[cog] * rsqrtf(v1[cog] + EPS);
        const float* wp = kw + ((size_t)cog * 64 + cc * 32 + hi * 8) * 9 + tap;
        #pragma unroll
        for (int e = 0; e < 8; ++e) v[e] = f2bf(wp[e * 9] * inv);
    }
    *(s16x8*)&Wb[(size_t)u * 8] = v;
}

// ---------------- xT: x f32 [b,c,hw] -> bf16 [b][oct24][hw][8] ----------------
__global__ __launch_bounds__(256) void k_xt(const float* __restrict__ x,
                                            unsigned short* __restrict__ xT) {
    int b = blockIdx.y;
    int n0 = blockIdx.x * SPX;
    int t = threadIdx.x;
    __shared__ unsigned short L[SPX * BPS];
    for (int u = t; u < SPX * 24; u += 256) {
        int px = u & (SPX - 1);
        int oc = u >> 7;
        int n = n0 + px;
        s16x8 v = {0, 0, 0, 0, 0, 0, 0, 0};
        if (n < HW) {
            const float* xp = x + ((size_t)b * C + oc * 8) * HW + n;
            #pragma unroll
            for (int j = 0; j < 8; ++j) v[j] = f2bf(xp[(size_t)j * HW]);
        }
        *(s16x8*)&L[px * BPS + oc * 8] = v;
    }
    __syncthreads();
    for (int u = t; u < SPX * 24; u += 256) {
        int oc = u >> 7, row = u & 127;
        int n = n0 + row;
        if (n < HW)
            *(s16x8*)&xT[(((size_t)b * 24 + oc) * HW + n) * 8] =
                *(s16x8*)&L[row * BPS + oc * 8];
    }
}

// ---------------- pool6: x (b,c,120,120) -> P (b,c,36) ----------------
__global__ __launch_bounds__(256) void k_pool(const float* __restrict__ x,
                                              float* __restrict__ P) {
    int bc = blockIdx.x;
    const float* xp = x + (size_t)bc * HW;
    __shared__ float acc[AN];
    int tid = threadIdx.x;
    if (tid < AN) acc[tid] = 0.f;
    __syncthreads();
    for (int s = tid; s < 720; s += 256) {
        int y = s / 6, xs = s % 6;
        const float4* p4 = (const float4*)(xp + y * W + xs * 20);
        float sum = 0.f;
        #pragma unroll
        for (int i = 0; i < 5; ++i) {
            float4 v = p4[i];
            sum += v.x + v.y + v.z + v.w;
        }
        atomicAdd(&acc[(y / 20) * 6 + xs], sum);
    }
    __syncthreads();
    if (tid < AN) P[(size_t)bc * AN + tid] = acc[tid] * (1.f / 400.f);
}

// ---------------- v = val_w (192x192) * P (per b) ----------------
__global__ __launch_bounds__(256) void k_val(const float* __restrict__ valw,
                                             const float* __restrict__ P,
                                             float* __restrict__ V) {
    int b = blockIdx.x;
    __shared__ float Pl[C * AN];
    int tid = threadIdx.x;
    for (int i = tid; i < C * AN; i += 256) Pl[i] = P[(size_t)b * C * AN + i];
    __syncthreads();
    for (int o = tid; o < C * AN; o += 256) {
        int cc = o / AN, a = o % AN;
        float s = 0.f;
        for (int k = 0; k < C; ++k) s += valw[cc * C + k] * Pl[k * AN + a];
        V[(size_t)b * C * AN + o] = s;
    }
}

// ------------- grouped 3x3 conv + BN1 + ReLU, implicit-GEMM MFMA -------------
// block = (y-pair, g, b): 2 rows x 128 px x 64 co; 4 waves, each 64px x 64co.
// xl [oct4][row4][XLD px] 16B units; wl [(tap*4+hi)*WLD+co] 16B units.
__global__ __launch_bounds__(256, 2) void k_conv_mfma(
        const unsigned short* __restrict__ xT, const unsigned short* __restrict__ Wb,
        const float* __restrict__ g1, const float* __restrict__ b1,
        const float* __restrict__ m1, const float* __restrict__ v1,
        float* __restrict__ k1f, unsigned short* __restrict__ k1b, int writeF32) {
    int yp = blockIdx.x, g = blockIdx.y, b = blockIdx.z;
    int y0 = yp * 2;
    int t = threadIdx.x;
    __shared__ short xl[4 * 4 * XLD * 8];     // 34,048 B
    __shared__ short wl[9 * 4 * WLD * 8];     // 37,440 B

    int w = t >> 6, l = t & 63, lr = l & 15, hi = l >> 4;
    int ry = w >> 1, xh = w & 1;
    f32x4 acc[4][4];
    #pragma unroll
    for (int mt = 0; mt < 4; ++mt)
        #pragma unroll
        for (int nt = 0; nt < 4; ++nt)
            acc[mt][nt] = (f32x4){0.f, 0.f, 0.f, 0.f};

    for (int cc = 0; cc < 2; ++cc) {
        // ---- stage x: 2128 coalesced b128 copies, identity LDS mapping ----
        for (int u = t; u < 4 * 4 * XLD; u += 256) {
            int oct = u / (4 * XLD), rem = u - oct * (4 * XLD);
            int r = rem / XLD, p = rem - r * XLD;
            int yy = y0 + r - 1, px = p - 1;
            s16x8 v = {0, 0, 0, 0, 0, 0, 0, 0};
            if (p < 132 && yy >= 0 && yy < H && px >= 0 && px < W)
                v = *(const s16x8*)&xT[(((size_t)b * 24 + g * 8 + cc * 4 + oct) * HW +
                                        yy * W + px) * 8];
            *(s16x8*)&xl[u * 8] = v;
        }
        // ---- stage w: straight copy from prefolded Wb ----
        {
            const s16x8* wsrc = (const s16x8*)Wb + (size_t)(g * 2 + cc) * 2340;
            for (int u = t; u < 2340; u += 256)
                *(s16x8*)&wl[u * 8] = wsrc[u];
        }
        __syncthreads();
        #pragma unroll
        for (int tap = 0; tap < 9; ++tap) {
            int ky = tap / 3, kx = tap % 3;
            s16x8 B[4];
            #pragma unroll
            for (int nt = 0; nt < 4; ++nt)
                B[nt] = *(const s16x8*)&wl[((tap * 4 + hi) * WLD + nt * 16 + lr) * 8];
            s16x8 A[4];
            #pragma unroll
            for (int mt = 0; mt < 4; ++mt)
                A[mt] = *(const s16x8*)&xl[((hi * 4 + ry + ky) * XLD +
                                            xh * 64 + mt * 16 + lr + kx) * 8];
            #pragma unroll
            for (int mt = 0; mt < 4; ++mt)
                #pragma unroll
                for (int nt = 0; nt < 4; ++nt)
                    acc[mt][nt] = __builtin_amdgcn_mfma_f32_16x16x32_bf16(
                        A[mt], B[nt], acc[mt][nt], 0, 0, 0);
        }
        __syncthreads();
    }
    // ---- epilogue: +beta, ReLU, store ----
    int y = y0 + ry;
    #pragma unroll
    for (int nt = 0; nt < 4; ++nt) {
        int cog = g * CPG + nt * 16 + lr;
        float inv = g1[cog] * rsqrtf(v1[cog] + EPS);
        float beta = b1[cog] - m1[cog] * inv;
        #pragma unroll
        for (int mt = 0; mt < 4; ++mt) {
            int xcol = xh * 64 + mt * 16 + hi * 4;
            if (xcol >= 120) continue;
            float r0 = fmaxf(acc[mt][nt][0] + beta, 0.f);
            float r1 = fmaxf(acc[mt][nt][1] + beta, 0.f);
            float r2 = fmaxf(acc[mt][nt][2] + beta, 0.f);
            float r3 = fmaxf(acc[mt][nt][3] + beta, 0.f);
            size_t base = ((size_t)(b * C + cog)) * HW + y * W + xcol;
            if (writeF32) {
                *(float4*)&k1f[base] = make_float4(r0, r1, r2, r3);
            } else {
                u16x4 q;
                q[0] = (unsigned short)f2bf(r0); q[1] = (unsigned short)f2bf(r1);
                q[2] = (unsigned short)f2bf(r2); q[3] = (unsigned short)f2bf(r3);
                *(u16x4*)&k1b[base] = q;
            }
        }
    }
}

// ------- scores via MFMA: S1[b,a,n] = agent . k1view, S2 = agent . xview (raw logits) -------
__global__ __launch_bounds__(256, 3) void k_scores_mfma(
        const float* __restrict__ Pp, const float* __restrict__ k1f,
        const unsigned short* __restrict__ k1b, const float* __restrict__ x,
        float* __restrict__ S1, float* __restrict__ S2) {
    int b = blockIdx.y;
    int n0 = blockIdx.x * SPX;
    int t = threadIdx.x;
    int w = t >> 6, l = t & 63, lr = l & 15, hi = l >> 4;
    __shared__ short Bp[SPX * BPS];

    s16x8 afr[3][6];
    const float* ab = Pp + (size_t)b * (C * AN);
    #pragma unroll
    for (int mt = 0; mt < 3; ++mt) {
        int row = mt * 16 + lr;
        #pragma unroll
        for (int kc = 0; kc < 6; ++kc) {
            s16x8 v = {0, 0, 0, 0, 0, 0, 0, 0};
            if (row < AN) {
                const float4* ap = (const float4*)(ab + row * C + kc * 32 + hi * 8);
                v = cvt8(ap[0], ap[1]);
            }
            afr[mt][kc] = v;
        }
    }

    #pragma unroll 1
    for (int s = 0; s < 2; ++s) {
        __syncthreads();
        if (s == 0 && k1b) {
            const unsigned short* src = k1b + (size_t)b * C * HW + (size_t)n0 * C;
            for (int i = t; i < SPX * 24; i += 256) {
                int row = i / 24, o = i - row * 24;
                s16x8 v = {0, 0, 0, 0, 0, 0, 0, 0};
                if (n0 + row < HW) v = *(const s16x8*)&src[row * C + o * 8];
                *(s16x8*)&Bp[row * BPS + o * 8] = v;
            }
        } else {
            const float* sf = (s == 0) ? k1f : x;
            const float4* src = (const float4*)(sf + (size_t)b * C * HW + (size_t)n0 * C);
            for (int i = t; i < SPX * 24; i += 256) {
                int row = i / 24, c8 = (i - row * 24) * 8;
                s16x8 v = {0, 0, 0, 0, 0, 0, 0, 0};
                if (n0 + row < HW)
                    v = cvt8(src[row * 48 + c8 / 4], src[row * 48 + c8 / 4 + 1]);
                *(s16x8*)&Bp[row * BPS + c8] = v;
            }
        }
        __syncthreads();
        f32x4 acc[3][2];
        #pragma unroll
        for (int mt = 0; mt < 3; ++mt)
            #pragma unroll
            for (int pt = 0; pt < 2; ++pt)
                acc[mt][pt] = (f32x4){0.f, 0.f, 0.f, 0.f};
        #pragma unroll
        for (int kc = 0; kc < 6; ++kc) {
            s16x8 bf[2];
            #pragma unroll
            for (int pt = 0; pt < 2; ++pt) {
                int px = (w * 2 + pt) * 16 + lr;
                bf[pt] = *(const s16x8*)&Bp[px * BPS + kc * 32 + hi * 8];
            }
            #pragma unroll
            for (int mt = 0; mt < 3; ++mt)
                #pragma unroll
                for (int pt = 0; pt < 2; ++pt)
                    acc[mt][pt] = __builtin_amdgcn_mfma_f32_16x16x32_bf16(
                        afr[mt][kc], bf[pt], acc[mt][pt], 0, 0, 0);
        }
        float* dst = (s == 0 ? S1 : S2) + (size_t)b * AN * HW + n0;
        #pragma unroll
        for (int mt = 0; mt < 3; ++mt)
            #pragma unroll
            for (int pt = 0; pt < 2; ++pt) {
                int px = (w * 2 + pt) * 16 + lr;
                if (n0 + px >= HW) continue;
                #pragma unroll
                for (int r = 0; r < 4; ++r) {
                    int a = mt * 16 + hi * 4 + r;
                    if (a < AN) dst[(size_t)a * HW + px] = acc[mt][pt][r];
                }
            }
    }
}

// ---------------- per-row (b,a) stats of S1: max and 1/sum(exp) ----------------
__global__ __launch_bounds__(256) void k_rowstats(const float* __restrict__ S,
                                                  float* __restrict__ stats) {
    int row = blockIdx.x;
    const float* p = S + (size_t)row * HW;
    int tid = threadIdx.x;
    __shared__ float red[4];
    float m = -1e30f;
    for (int i = tid; i < HW / 4; i += 256) {
        float4 v = ((const float4*)p)[i];
        m = fmaxf(m, fmaxf(fmaxf(v.x, v.y), fmaxf(v.z, v.w)));
    }
    #pragma unroll
    for (int off = 32; off > 0; off >>= 1) m = fmaxf(m, __shfl_down(m, off, 64));
    if ((tid & 63) == 0) red[tid >> 6] = m;
    __syncthreads();
    m = fmaxf(fmaxf(red[0], red[1]), fmaxf(red[2], red[3]));
    __syncthreads();
    float s = 0.f;
    for (int i = tid; i < HW / 4; i += 256) {
        float4 v = ((const float4*)p)[i];
        s += __expf(v.x - m) + __expf(v.y - m) + __expf(v.z - m) + __expf(v.w - m);
    }
    #pragma unroll
    for (int off = 32; off > 0; off >>= 1) s += __shfl_down(s, off, 64);
    if ((tid & 63) == 0) red[tid >> 6] = s;
    __syncthreads();
    if (tid == 0) {
        stats[row] = m;
        stats[576 + row] = 1.f / (red[0] + red[1] + red[2] + red[3]);
    }
}

// ------- fused: softmax(S1) via stats, softmax36(S2), conv1+BN2+ReLU, conv2(mean-folded) -------
__global__ __launch_bounds__(256) void k_fuse(const float* __restrict__ A1,
                                              const float* __restrict__ stats,
                                              const float* __restrict__ S2,
                                              const float* __restrict__ w1,
                                              const float* __restrict__ g2,
                                              const float* __restrict__ b2,
                                              const float* __restrict__ m2,
                                              const float* __restrict__ v2,
                                              const float* __restrict__ w2,
                                              const float* __restrict__ bias2,
                                              float* __restrict__ AM) {
    int b = blockIdx.y;
    int tid = threadIdx.x;
    int N = blockIdx.x * 256 + tid;
    __shared__ float W1f[MID * 72];
    __shared__ float b1f[MID];
    __shared__ float W2m[AN * MID];
    __shared__ float b2m[AN];
    __shared__ float sm_m[AN], sm_ri[AN];
    for (int i = tid; i < MID * 72; i += 256) {
        int m = i / 72;
        W1f[i] = w1[i] * (g2[m] * rsqrtf(v2[m] + EPS));
    }
    if (tid < MID) {
        float inv = g2[tid] * rsqrtf(v2[tid] + EPS);
        b1f[tid] = b2[tid] - m2[tid] * inv;
    }
    for (int i = tid; i < AN * MID; i += 256) {
        int a = i / MID, m = i % MID;
        float s = 0.f;
        #pragma unroll
        for (int k = 0; k < 9; ++k) s += w2[(a * 9 + k) * MID + m];
        W2m[i] = s * (1.f / 9.f);
    }
    if (tid < AN) {
        float s = 0.f;
        #pragma unroll
        for (int k = 0; k < 9; ++k) s += bias2[tid * 9 + k];
        b2m[tid] = s * (1.f / 9.f);
        sm_m[tid] = stats[b * AN + tid];
        sm_ri[tid] = stats[576 + b * AN + tid];
    }
    __syncthreads();
    if (N >= HW) return;
    float yv[72];
    const float* a1p = A1 + (size_t)b * AN * HW + N;
    #pragma unroll
    for (int j = 0; j < AN; ++j)
        yv[j] = __expf(a1p[(size_t)j * HW] - sm_m[j]) * sm_ri[j];
    const float* s2p = S2 + (size_t)b * AN * HW + N;
    float mx = -1e30f;
    #pragma unroll
    for (int j = 0; j < AN; ++j) {
        float v = s2p[(size_t)j * HW];
        yv[AN + j] = v;
        mx = fmaxf(mx, v);
    }
    float ssum = 0.f;
    #pragma unroll
    for (int j = 0; j < AN; ++j) {
        float e = __expf(yv[AN + j] - mx);
        yv[AN + j] = e;
        ssum += e;
    }
    float rs = 1.f / ssum;
    #pragma unroll
    for (int j = 0; j < AN; ++j) yv[AN + j] *= rs;
    float t[MID];
    #pragma unroll
    for (int m = 0; m < MID; ++m) {
        float a = b1f[m];
        #pragma unroll
        for (int j = 0; j < 72; ++j) a += W1f[m * 72 + j] * yv[j];
        t[m] = a > 0.f ? a : 0.f;
    }
    float* amp = AM + (size_t)b * AN * HW + N;
    #pragma unroll
    for (int a = 0; a < AN; ++a) {
        float acc = b2m[a];
        #pragma unroll
        for (int m = 0; m < MID; ++m) acc += W2m[a * MID + m] * t[m];
        amp[(size_t)a * HW] = acc;
    }
}

// ------- out[b,cc,n] = sum_a softmax36(att window)[a]*v[b,cc,a] + k1[b,cc,n] -------
__global__ __launch_bounds__(256) void k_out(const float* __restrict__ AM,
                                             const float* __restrict__ V,
                                             const unsigned short* __restrict__ k1b,
                                             float* __restrict__ outp) {
    int b = blockIdx.y;
    int tid = threadIdx.x;
    int N = blockIdx.x * 256 + tid;
    __shared__ float Vl[C * AN];
    for (int i = tid; i < C * AN; i += 256) Vl[i] = V[(size_t)b * C * AN + i];
    __syncthreads();
    if (N >= HW) return;
    int a = N / 400;
    int n0 = (N % 400) * AN;
    const float4* amr = (const float4*)(AM + ((size_t)b * AN + a) * HW + n0);
    float wv[AN];
    float mx = -1e30f;
    #pragma unroll
    for (int i4 = 0; i4 < 9; ++i4) {
        float4 q = amr[i4];
        wv[i4 * 4 + 0] = q.x; wv[i4 * 4 + 1] = q.y;
        wv[i4 * 4 + 2] = q.z; wv[i4 * 4 + 3] = q.w;
    }
    #pragma unroll
    for (int i = 0; i < AN; ++i) mx = fmaxf(mx, wv[i]);
    float s = 0.f;
    #pragma unroll
    for (int i = 0; i < AN; ++i) { wv[i] = __expf(wv[i] - mx); s += wv[i]; }
    float rs = 1.f / s;
    #pragma unroll
    for (int i = 0; i < AN; ++i) wv[i] *= rs;
    float* op = outp + (size_t)b * C * HW + N;
    if (k1b) {
        const unsigned short* kp = k1b + (size_t)b * C * HW + N;
        for (int cc = 0; cc < C; ++cc) {
            float acc = bf2f(kp[(size_t)cc * HW]);
            const float* vr = Vl + cc * AN;
            #pragma unroll
            for (int i4 = 0; i4 < 9; ++i4) {
                float4 vv = *(const float4*)(vr + i4 * 4);
                acc += wv[i4 * 4 + 0] * vv.x + wv[i4 * 4 + 1] * vv.y +
                       wv[i4 * 4 + 2] * vv.z + wv[i4 * 4 + 3] * vv.w;
            }
            op[(size_t)cc * HW] = acc;
        }
    } else {
        for (int cc = 0; cc < C; ++cc) {
            float acc = op[(size_t)cc * HW];
            const float* vr = Vl + cc * AN;
            #pragma unroll
            for (int i4 = 0; i4 < 9; ++i4) {
                float4 vv = *(const float4*)(vr + i4 * 4);
                acc += wv[i4 * 4 + 0] * vv.x + wv[i4 * 4 + 1] * vv.y +
                       wv[i4 * 4 + 2] * vv.z + wv[i4 * 4 + 3] * vv.w;
            }
            op[(size_t)cc * HW] = acc;
        }
    }
}

extern "C" void kernel_launch(void* const* d_in, const int* in_sizes, int n_in,
                              void* d_out, int out_size, void* d_ws, size_t ws_size,
                              hipStream_t stream) {
    const float* x      = (const float*)d_in[0];
    const float* key_w  = (const float*)d_in[1];
    const float* bn1_g  = (const float*)d_in[2];
    const float* bn1_b  = (const float*)d_in[3];
    const float* bn1_m  = (const float*)d_in[4];
    const float* bn1_v  = (const float*)d_in[5];
    const float* val_w  = (const float*)d_in[6];
    const float* att_w1 = (const float*)d_in[7];
    const float* bn2_g  = (const float*)d_in[8];
    const float* bn2_b  = (const float*)d_in[9];
    const float* bn2_m  = (const float*)d_in[10];
    const float* bn2_v  = (const float*)d_in[11];
    const float* att_w2 = (const float*)d_in[12];
    const float* att_b2 = (const float*)d_in[13];
    float* out = (float*)d_out;
    float* ws  = (float*)d_ws;

    size_t nP = (size_t)BS * C * AN;       // 110592
    size_t nS = (size_t)BS * AN * HW;      // 8294400
    size_t nWb = (size_t)NWU * 8 / 2;      // 56160 floats
    unsigned short* Wb = (unsigned short*)ws;
    float* P  = ws + nWb;
    float* V  = P + nP;
    float* ST = V + nP;                    // 1152 floats
    float* S1 = ST + 1152;
    float* S2 = S1 + nS;
    float* AM = S2 + nS;
    // xT (bf16 [b][24][hw][8], 88.5 MB) aliases S1+S2+part of AM: lifetime [k_xt..k_conv].
    unsigned short* xT = (unsigned short*)S1;
    size_t baseBytes = (nWb + nP * 2 + 1152 + 3 * nS) * sizeof(float);
    size_t k1bBytes  = (size_t)BS * C * HW * sizeof(unsigned short);
    unsigned short* k1b = (ws_size >= baseBytes + k1bBytes)
                              ? (unsigned short*)(AM + nS) : nullptr;
    int writeF32 = (k1b == nullptr) ? 1 : 0;

    k_wfold<<<(NWU + 255) / 256, 256, 0, stream>>>(key_w, bn1_g, bn1_v, Wb);
    k_xt<<<dim3((HW + SPX - 1) / SPX, BS), 256, 0, stream>>>(x, xT);
    k_pool<<<BS * C, 256, 0, stream>>>(x, P);
    k_val<<<BS, 256, 0, stream>>>(val_w, P, V);
    k_conv_mfma<<<dim3(H / 2, 3, BS), 256, 0, stream>>>(
        xT, Wb, bn1_g, bn1_b, bn1_m, bn1_v, out, k1b, writeF32);
    k_scores_mfma<<<dim3((HW + SPX - 1) / SPX, BS), 256, 0, stream>>>(
        P, out, k1b, x, S1, S2);
    k_rowstats<<<BS * AN, 256, 0, stream>>>(S1, ST);
    k_fuse<<<dim3((HW + 255) / 256, BS), 256, 0, stream>>>(
        S1, ST, S2, att_w1, bn2_g, bn2_b, bn2_m, bn2_v, att_w2, att_b2, AM);
    k_out<<<dim3((HW + 255) / 256, BS), 256, 0, stream>>>(AM, V, k1b, out);
}

// Round 6
// 562.859 us; speedup vs baseline: 9.6652x; 1.1081x over previous
//
#include <hip/hip_runtime.h>
#include <hip/hip_bf16.h>
#include <math.h>

#define BS 16
#define C 192
#define H 120
#define W 120
#define HW 14400
#define AN 36
#define MID 18
#define CPG 64
#define EPS 1e-5f
#define SPX 128
#define BPS 200
#define NWQ 13824   // 3g * 2cc * 9tap * 4hi * 64co units (16B each)
#define XROWS 122   // padded rows in xTp (y -1..120)
#define XCOLS 132   // padded cols in xTp (px -1..130)

typedef __attribute__((ext_vector_type(8))) short s16x8;
typedef __attribute__((ext_vector_type(4))) float f32x4;
typedef __attribute__((ext_vector_type(4))) unsigned short u16x4;

static __device__ __forceinline__ short f2bf(float f) {
    union { float f; unsigned u; } v; v.f = f;
    unsigned r = (v.u + 0x7FFF + ((v.u >> 16) & 1)) >> 16;
    return (short)r;
}
static __device__ __forceinline__ float bf2f(unsigned short u) {
    union { unsigned u; float f; } v; v.u = ((unsigned)u) << 16;
    return v.f;
}
static __device__ __forceinline__ s16x8 cvt8(float4 f0, float4 f1) {
    s16x8 v;
    v[0] = f2bf(f0.x); v[1] = f2bf(f0.y); v[2] = f2bf(f0.z); v[3] = f2bf(f0.w);
    v[4] = f2bf(f1.x); v[5] = f2bf(f1.y); v[6] = f2bf(f1.z); v[7] = f2bf(f1.w);
    return v;
}

// ------- fold BN1 into key_w, bf16, B-fragment layout: [g][cc][(tap*4+hi)*64+co] 16B units -------
__global__ __launch_bounds__(256) void k_wfold(const float* __restrict__ kw,
                                               const float* __restrict__ g1,
                                               const float* __restrict__ v1,
                                               unsigned short* __restrict__ Wq) {
    int u = blockIdx.x * 256 + threadIdx.x;
    if (u >= NWQ) return;
    int gc = u / 2304, rem = u - gc * 2304;   // 2304 = 36*64
    int g = gc >> 1, cc = gc & 1;
    int th = rem >> 6, co = rem & 63;
    int tap = th >> 2, hi = th & 3;
    int cog = g * 64 + co;
    float inv = g1[cog] * rsqrtf(v1[cog] + EPS);
    const float* wp = kw + ((size_t)cog * 64 + cc * 32 + hi * 8) * 9 + tap;
    s16x8 v;
    #pragma unroll
    for (int e = 0; e < 8; ++e) v[e] = f2bf(wp[e * 9] * inv);
    *(s16x8*)&Wq[(size_t)u * 8] = v;
}

// ------- xTp: x f32 [b,c,hw] -> bf16 [b][oct24][row 122][col 132][8], zero-padded halo -------
__global__ __launch_bounds__(256) void k_xt(const float* __restrict__ x,
                                            unsigned short* __restrict__ xTp) {
    int y = blockIdx.x, b = blockIdx.y;
    int t = threadIdx.x;
    __shared__ unsigned short L[120 * 200];
    for (int u = t; u < 24 * 120; u += 256) {
        int oc = u / 120, px = u - oc * 120;
        const float* xp = x + ((size_t)b * C + oc * 8) * HW + y * W + px;
        s16x8 v;
        #pragma unroll
        for (int j = 0; j < 8; ++j) v[j] = f2bf(xp[(size_t)j * HW]);
        *(s16x8*)&L[px * 200 + oc * 8] = v;
    }
    __syncthreads();
    for (int u = t; u < 24 * XCOLS; u += 256) {
        int oc = u / XCOLS, p = u - oc * XCOLS;
        int px = p - 1;
        s16x8 v = {0, 0, 0, 0, 0, 0, 0, 0};
        if (px >= 0 && px < 120) v = *(const s16x8*)&L[px * 200 + oc * 8];
        *(s16x8*)&xTp[(((size_t)(b * 24 + oc)) * XROWS + (y + 1)) * XCOLS * 8 + p * 8] = v;
    }
    if (y == 0 || y == H - 1) {
        int r = (y == 0) ? 0 : XROWS - 1;
        s16x8 z = {0, 0, 0, 0, 0, 0, 0, 0};
        for (int u = t; u < 24 * XCOLS; u += 256) {
            int oc = u / XCOLS, p = u - oc * XCOLS;
            *(s16x8*)&xTp[(((size_t)(b * 24 + oc)) * XROWS + r) * XCOLS * 8 + p * 8] = z;
        }
    }
}

// ---------------- pool6: x (b,c,120,120) -> P (b,c,36) ----------------
__global__ __launch_bounds__(256) void k_pool(const float* __restrict__ x,
                                              float* __restrict__ P) {
    int bc = blockIdx.x;
    const float* xp = x + (size_t)bc * HW;
    __shared__ float acc[AN];
    int tid = threadIdx.x;
    if (tid < AN) acc[tid] = 0.f;
    __syncthreads();
    for (int s = tid; s < 720; s += 256) {
        int y = s / 6, xs = s % 6;
        const float4* p4 = (const float4*)(xp + y * W + xs * 20);
        float sum = 0.f;
        #pragma unroll
        for (int i = 0; i < 5; ++i) {
            float4 v = p4[i];
            sum += v.x + v.y + v.z + v.w;
        }
        atomicAdd(&acc[(y / 20) * 6 + xs], sum);
    }
    __syncthreads();
    if (tid < AN) P[(size_t)bc * AN + tid] = acc[tid] * (1.f / 400.f);
}

// ---------------- v = val_w (192x192) * P (per b) ----------------
__global__ __launch_bounds__(256) void k_val(const float* __restrict__ valw,
                                             const float* __restrict__ P,
                                             float* __restrict__ V) {
    int b = blockIdx.x;
    __shared__ float Pl[C * AN];
    int tid = threadIdx.x;
    for (int i = tid; i < C * AN; i += 256) Pl[i] = P[(size_t)b * C * AN + i];
    __syncthreads();
    for (int o = tid; o < C * AN; o += 256) {
        int cc = o / AN, a = o % AN;
        float s = 0.f;
        for (int k = 0; k < C; ++k) s += valw[cc * C + k] * Pl[k * AN + a];
        V[(size_t)b * C * AN + o] = s;
    }
}

// ------------- grouped 3x3 conv + BN1 + ReLU, implicit-GEMM MFMA -------------
// block = (y-pair, g, b): 2 rows x 128 px x 64 co; 4 waves each 64px x 64co.
// x tile in LDS (32 KB, branch-free staging from padded xTp); B-fragments direct
// from global Wq (L2-resident) with 1-tap register prefetch. 4 blocks/CU.
__global__ __launch_bounds__(256, 4) void k_conv_mfma(
        const unsigned short* __restrict__ xTp, const unsigned short* __restrict__ Wq,
        const float* __restrict__ g1, const float* __restrict__ b1,
        const float* __restrict__ m1, const float* __restrict__ v1,
        float* __restrict__ k1f, unsigned short* __restrict__ k1b, int writeF32) {
    int yp = blockIdx.x, g = blockIdx.y, b = blockIdx.z;
    int y0 = yp * 2;
    int t = threadIdx.x;
    __shared__ short xl[(2048 + 2) * 8];      // 16 rows x 128 units (+2 guard)

    int w = t >> 6, l = t & 63, lr = l & 15, hi = l >> 4;
    int ry = w >> 1, xh = w & 1;
    f32x4 acc[4][4];
    #pragma unroll
    for (int mt = 0; mt < 4; ++mt)
        #pragma unroll
        for (int nt = 0; nt < 4; ++nt)
            acc[mt][nt] = (f32x4){0.f, 0.f, 0.f, 0.f};

    for (int cc = 0; cc < 2; ++cc) {
        if (cc) __syncthreads();
        // stage x: 2048 branch-free contiguous b128 copies (8 per thread)
        const unsigned short* xbase =
            xTp + ((size_t)((b * 24 + g * 8 + cc * 4) * XROWS) + y0) * XCOLS * 8;
        #pragma unroll
        for (int k = 0; k < 8; ++k) {
            int u = t + 256 * k;
            int run = u >> 7, p = u & 127;
            int oct = run >> 2, r = run & 3;
            s16x8 v = *(const s16x8*)&xbase[((size_t)(oct * XROWS + r)) * XCOLS * 8 + p * 8];
            *(s16x8*)&xl[u * 8] = v;
        }
        __syncthreads();
        const s16x8* wq = (const s16x8*)Wq + (size_t)(g * 2 + cc) * 2304;
        s16x8 Bn[4];
        #pragma unroll
        for (int nt = 0; nt < 4; ++nt) Bn[nt] = wq[hi * 64 + nt * 16 + lr];
        #pragma unroll
        for (int tap = 0; tap < 9; ++tap) {
            int ky = tap / 3, kx = tap % 3;
            s16x8 Bc[4];
            #pragma unroll
            for (int nt = 0; nt < 4; ++nt) Bc[nt] = Bn[nt];
            if (tap < 8) {
                #pragma unroll
                for (int nt = 0; nt < 4; ++nt)
                    Bn[nt] = wq[((tap + 1) * 4 + hi) * 64 + nt * 16 + lr];
            }
            s16x8 A[4];
            #pragma unroll
            for (int mt = 0; mt < 4; ++mt) {
                int col = xh * 64 + mt * 16 + lr + kx;
                A[mt] = *(const s16x8*)&xl[((hi * 4 + ry + ky) * 128 + col) * 8];
            }
            #pragma unroll
            for (int mt = 0; mt < 4; ++mt)
                #pragma unroll
                for (int nt = 0; nt < 4; ++nt)
                    acc[mt][nt] = __builtin_amdgcn_mfma_f32_16x16x32_bf16(
                        A[mt], Bc[nt], acc[mt][nt], 0, 0, 0);
        }
    }
    // ---- epilogue: +beta, ReLU, store ----
    int y = y0 + ry;
    #pragma unroll
    for (int nt = 0; nt < 4; ++nt) {
        int cog = g * CPG + nt * 16 + lr;
        float inv = g1[cog] * rsqrtf(v1[cog] + EPS);
        float beta = b1[cog] - m1[cog] * inv;
        #pragma unroll
        for (int mt = 0; mt < 4; ++mt) {
            int xcol = xh * 64 + mt * 16 + hi * 4;
            if (xcol >= 120) continue;
            float r0 = fmaxf(acc[mt][nt][0] + beta, 0.f);
            float r1 = fmaxf(acc[mt][nt][1] + beta, 0.f);
            float r2 = fmaxf(acc[mt][nt][2] + beta, 0.f);
            float r3 = fmaxf(acc[mt][nt][3] + beta, 0.f);
            size_t base = ((size_t)(b * C + cog)) * HW + y * W + xcol;
            if (writeF32) {
                *(float4*)&k1f[base] = make_float4(r0, r1, r2, r3);
            } else {
                u16x4 q;
                q[0] = (unsigned short)f2bf(r0); q[1] = (unsigned short)f2bf(r1);
                q[2] = (unsigned short)f2bf(r2); q[3] = (unsigned short)f2bf(r3);
                *(u16x4*)&k1b[base] = q;
            }
        }
    }
}

// ------- scores via MFMA: S1[b,a,n] = agent . k1view, S2 = agent . xview (raw logits) -------
__global__ __launch_bounds__(256, 3) void k_scores_mfma(
        const float* __restrict__ Pp, const float* __restrict__ k1f,
        const unsigned short* __restrict__ k1b, const float* __restrict__ x,
        float* __restrict__ S1, float* __restrict__ S2) {
    int b = blockIdx.y;
    int n0 = blockIdx.x * SPX;
    int t = threadIdx.x;
    int w = t >> 6, l = t & 63, lr = l & 15, hi = l >> 4;
    __shared__ short Bp[SPX * BPS];

    s16x8 afr[3][6];
    const float* ab = Pp + (size_t)b * (C * AN);
    #pragma unroll
    for (int mt = 0; mt < 3; ++mt) {
        int row = mt * 16 + lr;
        #pragma unroll
        for (int kc = 0; kc < 6; ++kc) {
            s16x8 v = {0, 0, 0, 0, 0, 0, 0, 0};
            if (row < AN) {
                const float4* ap = (const float4*)(ab + row * C + kc * 32 + hi * 8);
                v = cvt8(ap[0], ap[1]);
            }
            afr[mt][kc] = v;
        }
    }

    #pragma unroll 1
    for (int s = 0; s < 2; ++s) {
        __syncthreads();
        if (s == 0 && k1b) {
            const unsigned short* src = k1b + (size_t)b * C * HW + (size_t)n0 * C;
            for (int i = t; i < SPX * 24; i += 256) {
                int row = i / 24, o = i - row * 24;
                s16x8 v = {0, 0, 0, 0, 0, 0, 0, 0};
                if (n0 + row < HW) v = *(const s16x8*)&src[row * C + o * 8];
                *(s16x8*)&Bp[row * BPS + o * 8] = v;
            }
        } else {
            const float* sf = (s == 0) ? k1f : x;
            const float4* src = (const float4*)(sf + (size_t)b * C * HW + (size_t)n0 * C);
            for (int i = t; i < SPX * 24; i += 256) {
                int row = i / 24, c8 = (i - row * 24) * 8;
                s16x8 v = {0, 0, 0, 0, 0, 0, 0, 0};
                if (n0 + row < HW)
                    v = cvt8(src[row * 48 + c8 / 4], src[row * 48 + c8 / 4 + 1]);
                *(s16x8*)&Bp[row * BPS + c8] = v;
            }
        }
        __syncthreads();
        f32x4 acc[3][2];
        #pragma unroll
        for (int mt = 0; mt < 3; ++mt)
            #pragma unroll
            for (int pt = 0; pt < 2; ++pt)
                acc[mt][pt] = (f32x4){0.f, 0.f, 0.f, 0.f};
        #pragma unroll
        for (int kc = 0; kc < 6; ++kc) {
            s16x8 bf[2];
            #pragma unroll
            for (int pt = 0; pt < 2; ++pt) {
                int px = (w * 2 + pt) * 16 + lr;
                bf[pt] = *(const s16x8*)&Bp[px * BPS + kc * 32 + hi * 8];
            }
            #pragma unroll
            for (int mt = 0; mt < 3; ++mt)
                #pragma unroll
                for (int pt = 0; pt < 2; ++pt)
                    acc[mt][pt] = __builtin_amdgcn_mfma_f32_16x16x32_bf16(
                        afr[mt][kc], bf[pt], acc[mt][pt], 0, 0, 0);
        }
        float* dst = (s == 0 ? S1 : S2) + (size_t)b * AN * HW + n0;
        #pragma unroll
        for (int mt = 0; mt < 3; ++mt)
            #pragma unroll
            for (int pt = 0; pt < 2; ++pt) {
                int px = (w * 2 + pt) * 16 + lr;
                if (n0 + px >= HW) continue;
                #pragma unroll
                for (int r = 0; r < 4; ++r) {
                    int a = mt * 16 + hi * 4 + r;
                    if (a < AN) dst[(size_t)a * HW + px] = acc[mt][pt][r];
                }
            }
    }
}

// ---------------- per-row (b,a) stats of S1: max and 1/sum(exp) ----------------
__global__ __launch_bounds__(256) void k_rowstats(const float* __restrict__ S,
                                                  float* __restrict__ stats) {
    int row = blockIdx.x;
    const float* p = S + (size_t)row * HW;
    int tid = threadIdx.x;
    __shared__ float red[4];
    float m = -1e30f;
    for (int i = tid; i < HW / 4; i += 256) {
        float4 v = ((const float4*)p)[i];
        m = fmaxf(m, fmaxf(fmaxf(v.x, v.y), fmaxf(v.z, v.w)));
    }
    #pragma unroll
    for (int off = 32; off > 0; off >>= 1) m = fmaxf(m, __shfl_down(m, off, 64));
    if ((tid & 63) == 0) red[tid >> 6] = m;
    __syncthreads();
    m = fmaxf(fmaxf(red[0], red[1]), fmaxf(red[2], red[3]));
    __syncthreads();
    float s = 0.f;
    for (int i = tid; i < HW / 4; i += 256) {
        float4 v = ((const float4*)p)[i];
        s += __expf(v.x - m) + __expf(v.y - m) + __expf(v.z - m) + __expf(v.w - m);
    }
    #pragma unroll
    for (int off = 32; off > 0; off >>= 1) s += __shfl_down(s, off, 64);
    if ((tid & 63) == 0) red[tid >> 6] = s;
    __syncthreads();
    if (tid == 0) {
        stats[row] = m;
        stats[576 + row] = 1.f / (red[0] + red[1] + red[2] + red[3]);
    }
}

// ------- fused: softmax(S1) via stats, softmax36(S2), conv1+BN2+ReLU, conv2(mean-folded) -------
__global__ __launch_bounds__(256) void k_fuse(const float* __restrict__ A1,
                                              const float* __restrict__ stats,
                                              const float* __restrict__ S2,
                                              const float* __restrict__ w1,
                                              const float* __restrict__ g2,
                                              const float* __restrict__ b2,
                                              const float* __restrict__ m2,
                                              const float* __restrict__ v2,
                                              const float* __restrict__ w2,
                                              const float* __restrict__ bias2,
                                              float* __restrict__ AM) {
    int b = blockIdx.y;
    int tid = threadIdx.x;
    int N = blockIdx.x * 256 + tid;
    __shared__ float W1f[MID * 72];
    __shared__ float b1f[MID];
    __shared__ float W2m[AN * MID];
    __shared__ float b2m[AN];
    __shared__ float sm_m[AN], sm_ri[AN];
    for (int i = tid; i < MID * 72; i += 256) {
        int m = i / 72;
        W1f[i] = w1[i] * (g2[m] * rsqrtf(v2[m] + EPS));
    }
    if (tid < MID) {
        float inv = g2[tid] * rsqrtf(v2[tid] + EPS);
        b1f[tid] = b2[tid] - m2[tid] * inv;
    }
    for (int i = tid; i < AN * MID; i += 256) {
        int a = i / MID, m = i % MID;
        float s = 0.f;
        #pragma unroll
        for (int k = 0; k < 9; ++k) s += w2[(a * 9 + k) * MID + m];
        W2m[i] = s * (1.f / 9.f);
    }
    if (tid < AN) {
        float s = 0.f;
        #pragma unroll
        for (int k = 0; k < 9; ++k) s += bias2[tid * 9 + k];
        b2m[tid] = s * (1.f / 9.f);
        sm_m[tid] = stats[b * AN + tid];
        sm_ri[tid] = stats[576 + b * AN + tid];
    }
    __syncthreads();
    if (N >= HW) return;
    float yv[72];
    const float* a1p = A1 + (size_t)b * AN * HW + N;
    #pragma unroll
    for (int j = 0; j < AN; ++j)
        yv[j] = __expf(a1p[(size_t)j * HW] - sm_m[j]) * sm_ri[j];
    const float* s2p = S2 + (size_t)b * AN * HW + N;
    float mx = -1e30f;
    #pragma unroll
    for (int j = 0; j < AN; ++j) {
        float v = s2p[(size_t)j * HW];
        yv[AN + j] = v;
        mx = fmaxf(mx, v);
    }
    float ssum = 0.f;
    #pragma unroll
    for (int j = 0; j < AN; ++j) {
        float e = __expf(yv[AN + j] - mx);
        yv[AN + j] = e;
        ssum += e;
    }
    float rs = 1.f / ssum;
    #pragma unroll
    for (int j = 0; j < AN; ++j) yv[AN + j] *= rs;
    float t[MID];
    #pragma unroll
    for (int m = 0; m < MID; ++m) {
        float a = b1f[m];
        #pragma unroll
        for (int j = 0; j < 72; ++j) a += W1f[m * 72 + j] * yv[j];
        t[m] = a > 0.f ? a : 0.f;
    }
    float* amp = AM + (size_t)b * AN * HW + N;
    #pragma unroll
    for (int a = 0; a < AN; ++a) {
        float acc = b2m[a];
        #pragma unroll
        for (int m = 0; m < MID; ++m) acc += W2m[a * MID + m] * t[m];
        amp[(size_t)a * HW] = acc;
    }
}

// ------- out[b,cc,n] = sum_a softmax36(att window)[a]*v[b,cc,a] + k1[b,cc,n] -------
__global__ __launch_bounds__(256) void k_out(const float* __restrict__ AM,
                                             const float* __restrict__ V,
                                             const unsigned short* __restrict__ k1b,
                                             float* __restrict__ outp) {
    int b = blockIdx.y;
    int tid = threadIdx.x;
    int N = blockIdx.x * 256 + tid;
    __shared__ float Vl[C * AN];
    for (int i = tid; i < C * AN; i += 256) Vl[i] = V[(size_t)b * C * AN + i];
    __syncthreads();
    if (N >= HW) return;
    int a = N / 400;
    int n0 = (N % 400) * AN;
    const float4* amr = (const float4*)(AM + ((size_t)b * AN + a) * HW + n0);
    float wv[AN];
    float mx = -1e30f;
    #pragma unroll
    for (int i4 = 0; i4 < 9; ++i4) {
        float4 q = amr[i4];
        wv[i4 * 4 + 0] = q.x; wv[i4 * 4 + 1] = q.y;
        wv[i4 * 4 + 2] = q.z; wv[i4 * 4 + 3] = q.w;
    }
    #pragma unroll
    for (int i = 0; i < AN; ++i) mx = fmaxf(mx, wv[i]);
    float s = 0.f;
    #pragma unroll
    for (int i = 0; i < AN; ++i) { wv[i] = __expf(wv[i] - mx); s += wv[i]; }
    float rs = 1.f / s;
    #pragma unroll
    for (int i = 0; i < AN; ++i) wv[i] *= rs;
    float* op = outp + (size_t)b * C * HW + N;
    if (k1b) {
        const unsigned short* kp = k1b + (size_t)b * C * HW + N;
        for (int cc = 0; cc < C; ++cc) {
            float acc = bf2f(kp[(size_t)cc * HW]);
            const float* vr = Vl + cc * AN;
            #pragma unroll
            for (int i4 = 0; i4 < 9; ++i4) {
                float4 vv = *(const float4*)(vr + i4 * 4);
                acc += wv[i4 * 4 + 0] * vv.x + wv[i4 * 4 + 1] * vv.y +
                       wv[i4 * 4 + 2] * vv.z + wv[i4 * 4 + 3] * vv.w;
            }
            op[(size_t)cc * HW] = acc;
        }
    } else {
        for (int cc = 0; cc < C; ++cc) {
            float acc = op[(size_t)cc * HW];
            const float* vr = Vl + cc * AN;
            #pragma unroll
            for (int i4 = 0; i4 < 9; ++i4) {
                float4 vv = *(const float4*)(vr + i4 * 4);
                acc += wv[i4 * 4 + 0] * vv.x + wv[i4 * 4 + 1] * vv.y +
                       wv[i4 * 4 + 2] * vv.z + wv[i4 * 4 + 3] * vv.w;
            }
            op[(size_t)cc * HW] = acc;
        }
    }
}

extern "C" void kernel_launch(void* const* d_in, const int* in_sizes, int n_in,
                              void* d_out, int out_size, void* d_ws, size_t ws_size,
                              hipStream_t stream) {
    const float* x      = (const float*)d_in[0];
    const float* key_w  = (const float*)d_in[1];
    const float* bn1_g  = (const float*)d_in[2];
    const float* bn1_b  = (const float*)d_in[3];
    const float* bn1_m  = (const float*)d_in[4];
    const float* bn1_v  = (const float*)d_in[5];
    const float* val_w  = (const float*)d_in[6];
    const float* att_w1 = (const float*)d_in[7];
    const float* bn2_g  = (const float*)d_in[8];
    const float* bn2_b  = (const float*)d_in[9];
    const float* bn2_m  = (const float*)d_in[10];
    const float* bn2_v  = (const float*)d_in[11];
    const float* att_w2 = (const float*)d_in[12];
    const float* att_b2 = (const float*)d_in[13];
    float* out = (float*)d_out;
    float* ws  = (float*)d_ws;

    size_t nP = (size_t)BS * C * AN;       // 110592
    size_t nS = (size_t)BS * AN * HW;      // 8294400
    size_t nWq = (size_t)NWQ * 8 / 2;      // floats occupied by Wq
    unsigned short* Wq = (unsigned short*)ws;
    float* P  = ws + nWq;
    float* V  = P + nP;
    float* ST = V + nP;                    // 1152 floats
    float* S1 = ST + 1152;
    float* S2 = S1 + nS;
    float* AM = S2 + nS;
    // xTp (bf16 padded [b][24][122][132][8], ~98.9 MB) aliases S1..AM: lifetime [k_xt..k_conv].
    unsigned short* xTp = (unsigned short*)S1;
    size_t baseBytes = (nWq + nP * 2 + 1152 + 3 * nS) * sizeof(float);
    size_t k1bBytes  = (size_t)BS * C * HW * sizeof(unsigned short);
    unsigned short* k1b = (ws_size >= baseBytes + k1bBytes)
                              ? (unsigned short*)(AM + nS) : nullptr;
    int writeF32 = (k1b == nullptr) ? 1 : 0;

    k_wfold<<<(NWQ + 255) / 256, 256, 0, stream>>>(key_w, bn1_g, bn1_v, Wq);
    k_xt<<<dim3(H, BS), 256, 0, stream>>>(x, xTp);
    k_pool<<<BS * C, 256, 0, stream>>>(x, P);
    k_val<<<BS, 256, 0, stream>>>(val_w, P, V);
    k_conv_mfma<<<dim3(H / 2, 3, BS), 256, 0, stream>>>(
        xTp, Wq, bn1_g, bn1_b, bn1_m, bn1_v, out, k1b, writeF32);
    k_scores_mfma<<<dim3((HW + SPX - 1) / SPX, BS), 256, 0, stream>>>(
        P, out, k1b, x, S1, S2);
    k_rowstats<<<BS * AN, 256, 0, stream>>>(S1, ST);
    k_fuse<<<dim3((HW + 255) / 256, BS), 256, 0, stream>>>(
        S1, ST, S2, att_w1, bn2_g, bn2_b, bn2_m, bn2_v, att_w2, att_b2, AM);
    k_out<<<dim3((HW + 255) / 256, BS), 256, 0, stream>>>(AM, V, k1b, out);
}

// Round 8
// 522.417 us; speedup vs baseline: 10.4134x; 1.0774x over previous
//
#include <hip/hip_runtime.h>
#include <hip/hip_bf16.h>
#include <math.h>

#define BS 16
#define C 192
#define H 120
#define W 120
#define HW 14400
#define AN 36
#define MID 18
#define CPG 64
#define EPS 1e-5f
#define SPX 128
#define BPS 200
#define NWQ 13824   // 3g * 2cc * 9tap * 4hi * 64co units (16B each)
#define XROWS 122
#define XCOLS 132
#define OPX 64      // k_out pixels per block
#define WST 72      // k_out w LDS stride (shorts; 144B = 16B-aligned, bank-step 4)

typedef __attribute__((ext_vector_type(8))) short s16x8;
typedef __attribute__((ext_vector_type(4))) float f32x4;
typedef __attribute__((ext_vector_type(4))) unsigned short u16x4;

static __device__ __forceinline__ short f2bf(float f) {
    union { float f; unsigned u; } v; v.f = f;
    unsigned r = (v.u + 0x7FFF + ((v.u >> 16) & 1)) >> 16;
    return (short)r;
}
static __device__ __forceinline__ float bf2f(unsigned short u) {
    union { unsigned u; float f; } v; v.u = ((unsigned)u) << 16;
    return v.f;
}
static __device__ __forceinline__ s16x8 cvt8(float4 f0, float4 f1) {
    s16x8 v;
    v[0] = f2bf(f0.x); v[1] = f2bf(f0.y); v[2] = f2bf(f0.z); v[3] = f2bf(f0.w);
    v[4] = f2bf(f1.x); v[5] = f2bf(f1.y); v[6] = f2bf(f1.z); v[7] = f2bf(f1.w);
    return v;
}

// ------- fold BN1 into key_w, bf16, B-fragment layout -------
__global__ __launch_bounds__(256) void k_wfold(const float* __restrict__ kw,
                                               const float* __restrict__ g1,
                                               const float* __restrict__ v1,
                                               unsigned short* __restrict__ Wq) {
    int u = blockIdx.x * 256 + threadIdx.x;
    if (u >= NWQ) return;
    int gc = u / 2304, rem = u - gc * 2304;
    int g = gc >> 1, cc = gc & 1;
    int th = rem >> 6, co = rem & 63;
    int tap = th >> 2, hi = th & 3;
    int cog = g * 64 + co;
    float inv = g1[cog] * rsqrtf(v1[cog] + EPS);
    const float* wp = kw + ((size_t)cog * 64 + cc * 32 + hi * 8) * 9 + tap;
    s16x8 v;
    #pragma unroll
    for (int e = 0; e < 8; ++e) v[e] = f2bf(wp[e * 9] * inv);
    *(s16x8*)&Wq[(size_t)u * 8] = v;
}

// ------- xTp: x f32 [b,c,hw] -> bf16 [b][oct24][row 122][col 132][8], zero halo -------
__global__ __launch_bounds__(256) void k_xt(const float* __restrict__ x,
                                            unsigned short* __restrict__ xTp) {
    int y = blockIdx.x, b = blockIdx.y;
    int t = threadIdx.x;
    __shared__ unsigned short L[120 * 200];
    for (int u = t; u < 24 * 120; u += 256) {
        int oc = u / 120, px = u - oc * 120;
        const float* xp = x + ((size_t)b * C + oc * 8) * HW + y * W + px;
        s16x8 v;
        #pragma unroll
        for (int j = 0; j < 8; ++j) v[j] = f2bf(xp[(size_t)j * HW]);
        *(s16x8*)&L[px * 200 + oc * 8] = v;
    }
    __syncthreads();
    for (int u = t; u < 24 * XCOLS; u += 256) {
        int oc = u / XCOLS, p = u - oc * XCOLS;
        int px = p - 1;
        s16x8 v = {0, 0, 0, 0, 0, 0, 0, 0};
        if (px >= 0 && px < 120) v = *(const s16x8*)&L[px * 200 + oc * 8];
        *(s16x8*)&xTp[(((size_t)(b * 24 + oc)) * XROWS + (y + 1)) * XCOLS * 8 + p * 8] = v;
    }
    if (y == 0 || y == H - 1) {
        int r = (y == 0) ? 0 : XROWS - 1;
        s16x8 z = {0, 0, 0, 0, 0, 0, 0, 0};
        for (int u = t; u < 24 * XCOLS; u += 256) {
            int oc = u / XCOLS, p = u - oc * XCOLS;
            *(s16x8*)&xTp[(((size_t)(b * 24 + oc)) * XROWS + r) * XCOLS * 8 + p * 8] = z;
        }
    }
}

// ---------------- pool6: x (b,c,120,120) -> P (b,c,36) ----------------
__global__ __launch_bounds__(256) void k_pool(const float* __restrict__ x,
                                              float* __restrict__ P) {
    int bc = blockIdx.x;
    const float* xp = x + (size_t)bc * HW;
    __shared__ float acc[AN];
    int tid = threadIdx.x;
    if (tid < AN) acc[tid] = 0.f;
    __syncthreads();
    for (int s = tid; s < 720; s += 256) {
        int y = s / 6, xs = s % 6;
        const float4* p4 = (const float4*)(xp + y * W + xs * 20);
        float sum = 0.f;
        #pragma unroll
        for (int i = 0; i < 5; ++i) {
            float4 v = p4[i];
            sum += v.x + v.y + v.z + v.w;
        }
        atomicAdd(&acc[(y / 20) * 6 + xs], sum);
    }
    __syncthreads();
    if (tid < AN) P[(size_t)bc * AN + tid] = acc[tid] * (1.f / 400.f);
}

// ------- Vb[b][cc][64] bf16 = val_w @ pooled (a>=36 zero-padded) -------
__global__ __launch_bounds__(256) void k_val(const float* __restrict__ valw,
                                             const float* __restrict__ P,
                                             unsigned short* __restrict__ Vb) {
    int b = blockIdx.x;
    __shared__ float Pl[C * AN];
    int tid = threadIdx.x;
    for (int i = tid; i < C * AN; i += 256) Pl[i] = P[(size_t)b * C * AN + i];
    __syncthreads();
    for (int o = tid; o < C * 8; o += 256) {
        int cc = o >> 3, a8 = o & 7;
        s16x8 vv = {0, 0, 0, 0, 0, 0, 0, 0};
        #pragma unroll
        for (int j = 0; j < 8; ++j) {
            int a = a8 * 8 + j;
            if (a < AN) {
                float s = 0.f;
                for (int k = 0; k < C; ++k) s += valw[cc * C + k] * Pl[k * AN + a];
                vv[j] = f2bf(s);
            }
        }
        *(s16x8*)&Vb[((size_t)b * C + cc) * 64 + a8 * 8] = vv;
    }
}

// ------------- grouped 3x3 conv + BN1 + ReLU, implicit-GEMM MFMA -------------
__global__ __launch_bounds__(256, 4) void k_conv_mfma(
        const unsigned short* __restrict__ xTp, const unsigned short* __restrict__ Wq,
        const float* __restrict__ g1, const float* __restrict__ b1,
        const float* __restrict__ m1, const float* __restrict__ v1,
        float* __restrict__ k1f, unsigned short* __restrict__ k1b, int writeF32) {
    int yp = blockIdx.x, g = blockIdx.y, b = blockIdx.z;
    int y0 = yp * 2;
    int t = threadIdx.x;
    __shared__ short xl[(2048 + 2) * 8];

    int w = t >> 6, l = t & 63, lr = l & 15, hi = l >> 4;
    int ry = w >> 1, xh = w & 1;
    f32x4 acc[4][4];
    #pragma unroll
    for (int mt = 0; mt < 4; ++mt)
        #pragma unroll
        for (int nt = 0; nt < 4; ++nt)
            acc[mt][nt] = (f32x4){0.f, 0.f, 0.f, 0.f};

    for (int cc = 0; cc < 2; ++cc) {
        if (cc) __syncthreads();
        const unsigned short* xbase =
            xTp + ((size_t)((b * 24 + g * 8 + cc * 4) * XROWS) + y0) * XCOLS * 8;
        #pragma unroll
        for (int k = 0; k < 8; ++k) {
            int u = t + 256 * k;
            int run = u >> 7, p = u & 127;
            int oct = run >> 2, r = run & 3;
            s16x8 v = *(const s16x8*)&xbase[((size_t)(oct * XROWS + r)) * XCOLS * 8 + p * 8];
            *(s16x8*)&xl[u * 8] = v;
        }
        __syncthreads();
        const s16x8* wq = (const s16x8*)Wq + (size_t)(g * 2 + cc) * 2304;
        s16x8 Bn[4];
        #pragma unroll
        for (int nt = 0; nt < 4; ++nt) Bn[nt] = wq[hi * 64 + nt * 16 + lr];
        #pragma unroll
        for (int tap = 0; tap < 9; ++tap) {
            int ky = tap / 3, kx = tap % 3;
            s16x8 Bc[4];
            #pragma unroll
            for (int nt = 0; nt < 4; ++nt) Bc[nt] = Bn[nt];
            if (tap < 8) {
                #pragma unroll
                for (int nt = 0; nt < 4; ++nt)
                    Bn[nt] = wq[((tap + 1) * 4 + hi) * 64 + nt * 16 + lr];
            }
            s16x8 A[4];
            #pragma unroll
            for (int mt = 0; mt < 4; ++mt) {
                int col = xh * 64 + mt * 16 + lr + kx;
                A[mt] = *(const s16x8*)&xl[((hi * 4 + ry + ky) * 128 + col) * 8];
            }
            #pragma unroll
            for (int mt = 0; mt < 4; ++mt)
                #pragma unroll
                for (int nt = 0; nt < 4; ++nt)
                    acc[mt][nt] = __builtin_amdgcn_mfma_f32_16x16x32_bf16(
                        A[mt], Bc[nt], acc[mt][nt], 0, 0, 0);
        }
    }
    int y = y0 + ry;
    #pragma unroll
    for (int nt = 0; nt < 4; ++nt) {
        int cog = g * CPG + nt * 16 + lr;
        float inv = g1[cog] * rsqrtf(v1[cog] + EPS);
        float beta = b1[cog] - m1[cog] * inv;
        #pragma unroll
        for (int mt = 0; mt < 4; ++mt) {
            int xcol = xh * 64 + mt * 16 + hi * 4;
            if (xcol >= 120) continue;
            float r0 = fmaxf(acc[mt][nt][0] + beta, 0.f);
            float r1 = fmaxf(acc[mt][nt][1] + beta, 0.f);
            float r2 = fmaxf(acc[mt][nt][2] + beta, 0.f);
            float r3 = fmaxf(acc[mt][nt][3] + beta, 0.f);
            size_t base = ((size_t)(b * C + cog)) * HW + y * W + xcol;
            if (writeF32) {
                *(float4*)&k1f[base] = make_float4(r0, r1, r2, r3);
            } else {
                u16x4 q;
                q[0] = (unsigned short)f2bf(r0); q[1] = (unsigned short)f2bf(r1);
                q[2] = (unsigned short)f2bf(r2); q[3] = (unsigned short)f2bf(r3);
                *(u16x4*)&k1b[base] = q;
            }
        }
    }
}

// ------- scores via MFMA: S1 = agent . k1view, S2 = agent . xview -------
__global__ __launch_bounds__(256, 3) void k_scores_mfma(
        const float* __restrict__ Pp, const float* __restrict__ k1f,
        const unsigned short* __restrict__ k1b, const float* __restrict__ x,
        const unsigned short* __restrict__ xTp,
        float* __restrict__ S1, float* __restrict__ S2) {
    int b = blockIdx.y;
    int n0 = blockIdx.x * SPX;
    int t = threadIdx.x;
    int w = t >> 6, l = t & 63, lr = l & 15, hi = l >> 4;
    __shared__ short Bp[SPX * BPS];

    s16x8 afr[3][6];
    const float* ab = Pp + (size_t)b * (C * AN);
    #pragma unroll
    for (int mt = 0; mt < 3; ++mt) {
        int row = mt * 16 + lr;
        #pragma unroll
        for (int kc = 0; kc < 6; ++kc) {
            s16x8 v = {0, 0, 0, 0, 0, 0, 0, 0};
            if (row < AN) {
                const float4* ap = (const float4*)(ab + row * C + kc * 32 + hi * 8);
                v = cvt8(ap[0], ap[1]);
            }
            afr[mt][kc] = v;
        }
    }

    #pragma unroll 1
    for (int s = 0; s < 2; ++s) {
        __syncthreads();
        if (s == 0 && k1b) {
            const unsigned short* src = k1b + (size_t)b * C * HW + (size_t)n0 * C;
            for (int i = t; i < SPX * 24; i += 256) {
                int row = i / 24, o = i - row * 24;
                s16x8 v = {0, 0, 0, 0, 0, 0, 0, 0};
                if (n0 + row < HW) v = *(const s16x8*)&src[row * C + o * 8];
                *(s16x8*)&Bp[row * BPS + o * 8] = v;
            }
        } else if (s == 1 && xTp) {
            for (int i = t; i < SPX * 24; i += 256) {
                int row = i / 24, oc = i - row * 24;
                int n = n0 + row;
                s16x8 v = {0, 0, 0, 0, 0, 0, 0, 0};
                if (n < HW) {
                    int yy = n / 120, xx = n - yy * 120;
                    v = *(const s16x8*)&xTp[(((size_t)(b * 24 + oc)) * XROWS + yy + 1) *
                                            XCOLS * 8 + (xx + 1) * 8];
                }
                *(s16x8*)&Bp[row * BPS + oc * 8] = v;
            }
        } else {
            const float* sf = (s == 0) ? k1f : x;
            const float4* src = (const float4*)(sf + (size_t)b * C * HW + (size_t)n0 * C);
            for (int i = t; i < SPX * 24; i += 256) {
                int row = i / 24, c8 = (i - row * 24) * 8;
                s16x8 v = {0, 0, 0, 0, 0, 0, 0, 0};
                if (n0 + row < HW)
                    v = cvt8(src[row * 48 + c8 / 4], src[row * 48 + c8 / 4 + 1]);
                *(s16x8*)&Bp[row * BPS + c8] = v;
            }
        }
        __syncthreads();
        f32x4 acc[3][2];
        #pragma unroll
        for (int mt = 0; mt < 3; ++mt)
            #pragma unroll
            for (int pt = 0; pt < 2; ++pt)
                acc[mt][pt] = (f32x4){0.f, 0.f, 0.f, 0.f};
        #pragma unroll
        for (int kc = 0; kc < 6; ++kc) {
            s16x8 bf[2];
            #pragma unroll
            for (int pt = 0; pt < 2; ++pt) {
                int px = (w * 2 + pt) * 16 + lr;
                bf[pt] = *(const s16x8*)&Bp[px * BPS + kc * 32 + hi * 8];
            }
            #pragma unroll
            for (int mt = 0; mt < 3; ++mt)
                #pragma unroll
                for (int pt = 0; pt < 2; ++pt)
                    acc[mt][pt] = __builtin_amdgcn_mfma_f32_16x16x32_bf16(
                        afr[mt][kc], bf[pt], acc[mt][pt], 0, 0, 0);
        }
        float* dst = (s == 0 ? S1 : S2) + (size_t)b * AN * HW + n0;
        #pragma unroll
        for (int mt = 0; mt < 3; ++mt)
            #pragma unroll
            for (int pt = 0; pt < 2; ++pt) {
                int px = (w * 2 + pt) * 16 + lr;
                if (n0 + px >= HW) continue;
                #pragma unroll
                for (int r = 0; r < 4; ++r) {
                    int a = mt * 16 + hi * 4 + r;
                    if (a < AN) dst[(size_t)a * HW + px] = acc[mt][pt][r];
                }
            }
    }
}

// ---------------- per-row (b,a) stats of S1: max and 1/sum(exp) ----------------
__global__ __launch_bounds__(256) void k_rowstats(const float* __restrict__ S,
                                                  float* __restrict__ stats) {
    int row = blockIdx.x;
    const float* p = S + (size_t)row * HW;
    int tid = threadIdx.x;
    __shared__ float red[4];
    float m = -1e30f;
    for (int i = tid; i < HW / 4; i += 256) {
        float4 v = ((const float4*)p)[i];
        m = fmaxf(m, fmaxf(fmaxf(v.x, v.y), fmaxf(v.z, v.w)));
    }
    #pragma unroll
    for (int off = 32; off > 0; off >>= 1) m = fmaxf(m, __shfl_down(m, off, 64));
    if ((tid & 63) == 0) red[tid >> 6] = m;
    __syncthreads();
    m = fmaxf(fmaxf(red[0], red[1]), fmaxf(red[2], red[3]));
    __syncthreads();
    float s = 0.f;
    for (int i = tid; i < HW / 4; i += 256) {
        float4 v = ((const float4*)p)[i];
        s += __expf(v.x - m) + __expf(v.y - m) + __expf(v.z - m) + __expf(v.w - m);
    }
    #pragma unroll
    for (int off = 32; off > 0; off >>= 1) s += __shfl_down(s, off, 64);
    if ((tid & 63) == 0) red[tid >> 6] = s;
    __syncthreads();
    if (tid == 0) {
        stats[row] = m;
        stats[576 + row] = 1.f / (red[0] + red[1] + red[2] + red[3]);
    }
}

// ------- fused: softmax(S1) via stats, softmax36(S2), conv1+BN2+ReLU, conv2 -------
__global__ __launch_bounds__(256) void k_fuse(const float* __restrict__ A1,
                                              const float* __restrict__ stats,
                                              const float* __restrict__ S2,
                                              const float* __restrict__ w1,
                                              const float* __restrict__ g2,
                                              const float* __restrict__ b2,
                                              const float* __restrict__ m2,
                                              const float* __restrict__ v2,
                                              const float* __restrict__ w2,
                                              const float* __restrict__ bias2,
                                              float* __restrict__ AM) {
    int b = blockIdx.y;
    int tid = threadIdx.x;
    int N = blockIdx.x * 256 + tid;
    __shared__ float W1f[MID * 72];
    __shared__ float b1f[MID];
    __shared__ float W2m[AN * MID];
    __shared__ float b2m[AN];
    __shared__ float sm_m[AN], sm_ri[AN];
    for (int i = tid; i < MID * 72; i += 256) {
        int m = i / 72;
        W1f[i] = w1[i] * (g2[m] * rsqrtf(v2[m] + EPS));
    }
    if (tid < MID) {
        float inv = g2[tid] * rsqrtf(v2[tid] + EPS);
        b1f[tid] = b2[tid] - m2[tid] * inv;
    }
    for (int i = tid; i < AN * MID; i += 256) {
        int a = i / MID, m = i % MID;
        float s = 0.f;
        #pragma unroll
        for (int k = 0; k < 9; ++k) s += w2[(a * 9 + k) * MID + m];
        W2m[i] = s * (1.f / 9.f);
    }
    if (tid < AN) {
        float s = 0.f;
        #pragma unroll
        for (int k = 0; k < 9; ++k) s += bias2[tid * 9 + k];
        b2m[tid] = s * (1.f / 9.f);
        sm_m[tid] = stats[b * AN + tid];
        sm_ri[tid] = stats[576 + b * AN + tid];
    }
    __syncthreads();
    if (N >= HW) return;
    float yv[72];
    const float* a1p = A1 + (size_t)b * AN * HW + N;
    #pragma unroll
    for (int j = 0; j < AN; ++j)
        yv[j] = __expf(a1p[(size_t)j * HW] - sm_m[j]) * sm_ri[j];
    const float* s2p = S2 + (size_t)b * AN * HW + N;
    float mx = -1e30f;
    #pragma unroll
    for (int j = 0; j < AN; ++j) {
        float v = s2p[(size_t)j * HW];
        yv[AN + j] = v;
        mx = fmaxf(mx, v);
    }
    float ssum = 0.f;
    #pragma unroll
    for (int j = 0; j < AN; ++j) {
        float e = __expf(yv[AN + j] - mx);
        yv[AN + j] = e;
        ssum += e;
    }
    float rs = 1.f / ssum;
    #pragma unroll
    for (int j = 0; j < AN; ++j) yv[AN + j] *= rs;
    float t[MID];
    #pragma unroll
    for (int m = 0; m < MID; ++m) {
        float a = b1f[m];
        #pragma unroll
        for (int j = 0; j < 72; ++j) a += W1f[m * 72 + j] * yv[j];
        t[m] = a > 0.f ? a : 0.f;
    }
    float* amp = AM + (size_t)b * AN * HW + N;
    #pragma unroll
    for (int a = 0; a < AN; ++a) {
        float acc = b2m[a];
        #pragma unroll
        for (int m = 0; m < MID; ++m) acc += W2m[a * MID + m] * t[m];
        amp[(size_t)a * HW] = acc;
    }
}

// ------- out via MFMA: out[cc][n] = sum_a softmax36(AM window)[a]*Vb[cc][a] + k1 -------
__global__ __launch_bounds__(256) void k_out_mfma(const float* __restrict__ AM,
                                                  const unsigned short* __restrict__ Vb,
                                                  const unsigned short* __restrict__ k1b,
                                                  float* __restrict__ outp) {
    int b = blockIdx.y;
    int N0 = blockIdx.x * OPX;
    int t = threadIdx.x;
    __shared__ short wl[OPX * WST];

    // phase 1: per-pixel window softmax, 4 lanes/pixel
    {
        int p = t >> 2, q = t & 3;
        int N = N0 + p;
        int a = N / 400;
        int n0w = (N - a * 400) * AN;
        const float* amp = AM + ((size_t)b * AN + a) * HW + n0w;
        const int qoff = (q == 0) ? 0 : (q == 1) ? 12 : (q == 2) ? 20 : 32;
        const int qn4 = (q == 0) ? 3 : (q == 1) ? 2 : (q == 2) ? 3 : 1;
        float vals[12];
        const float4* ap = (const float4*)(amp + qoff);
        #pragma unroll
        for (int i = 0; i < 3; ++i) {
            if (i < qn4) {
                float4 v = ap[i];
                vals[i * 4 + 0] = v.x; vals[i * 4 + 1] = v.y;
                vals[i * 4 + 2] = v.z; vals[i * 4 + 3] = v.w;
            }
        }
        int cnt = qn4 * 4;
        float m = -1e30f;
        #pragma unroll
        for (int i = 0; i < 12; ++i) if (i < cnt) m = fmaxf(m, vals[i]);
        m = fmaxf(m, __shfl_xor(m, 1, 64));
        m = fmaxf(m, __shfl_xor(m, 2, 64));
        float s = 0.f;
        #pragma unroll
        for (int i = 0; i < 12; ++i)
            if (i < cnt) { vals[i] = __expf(vals[i] - m); s += vals[i]; }
        s += __shfl_xor(s, 1, 64);
        s += __shfl_xor(s, 2, 64);
        float rs = 1.f / s;
        #pragma unroll
        for (int i = 0; i < 12; ++i)
            if (i < cnt) wl[p * WST + qoff + i] = f2bf(vals[i] * rs);
        if (q == 3) {
            // zero the K-pad (a=36..63) so MFMA's second chunk reads true zeros
            #pragma unroll
            for (int i = 36; i < 64; ++i) wl[p * WST + i] = 0;
        }
    }
    __syncthreads();

    // phase 2: GEMM 192cc x 64px, K=36 (padded 64; both pads zero)
    int w = t >> 6, l = t & 63, lr = l & 15, hi = l >> 4;
    int cc0 = w * 48;
    const s16x8* vb = (const s16x8*)(Vb + (size_t)b * C * 64);
    s16x8 Af[3][2];
    #pragma unroll
    for (int mt = 0; mt < 3; ++mt)
        #pragma unroll
        for (int ch = 0; ch < 2; ++ch)
            Af[mt][ch] = vb[(cc0 + mt * 16 + lr) * 8 + ch * 4 + hi];
    f32x4 acc[3][4];
    #pragma unroll
    for (int mt = 0; mt < 3; ++mt)
        #pragma unroll
        for (int pt = 0; pt < 4; ++pt)
            acc[mt][pt] = (f32x4){0.f, 0.f, 0.f, 0.f};
    #pragma unroll
    for (int pt = 0; pt < 4; ++pt) {
        s16x8 Bf[2];
        #pragma unroll
        for (int ch = 0; ch < 2; ++ch)
            Bf[ch] = *(const s16x8*)&wl[(pt * 16 + lr) * WST + ch * 32 + hi * 8];
        #pragma unroll
        for (int ch = 0; ch < 2; ++ch)
            #pragma unroll
            for (int mt = 0; mt < 3; ++mt)
                acc[mt][pt] = __builtin_amdgcn_mfma_f32_16x16x32_bf16(
                    Af[mt][ch], Bf[ch], acc[mt][pt], 0, 0, 0);
    }
    // epilogue: + k1 residual
    #pragma unroll
    for (int mt = 0; mt < 3; ++mt)
        #pragma unroll
        for (int pt = 0; pt < 4; ++pt) {
            int px = pt * 16 + lr;
            #pragma unroll
            for (int r = 0; r < 4; ++r) {
                int cc = cc0 + mt * 16 + hi * 4 + r;
                size_t idx = ((size_t)(b * C + cc)) * HW + N0 + px;
                float res = k1b ? bf2f(k1b[idx]) : outp[idx];
                outp[idx] = acc[mt][pt][r] + res;
            }
        }
}

extern "C" void kernel_launch(void* const* d_in, const int* in_sizes, int n_in,
                              void* d_out, int out_size, void* d_ws, size_t ws_size,
                              hipStream_t stream) {
    const float* x      = (const float*)d_in[0];
    const float* key_w  = (const float*)d_in[1];
    const float* bn1_g  = (const float*)d_in[2];
    const float* bn1_b  = (const float*)d_in[3];
    const float* bn1_m  = (const float*)d_in[4];
    const float* bn1_v  = (const float*)d_in[5];
    const float* val_w  = (const float*)d_in[6];
    const float* att_w1 = (const float*)d_in[7];
    const float* bn2_g  = (const float*)d_in[8];
    const float* bn2_b  = (const float*)d_in[9];
    const float* bn2_m  = (const float*)d_in[10];
    const float* bn2_v  = (const float*)d_in[11];
    const float* att_w2 = (const float*)d_in[12];
    const float* att_b2 = (const float*)d_in[13];
    float* out = (float*)d_out;

    unsigned char* base = (unsigned char*)d_ws;
    size_t off = 0;
    unsigned short* Wq = (unsigned short*)(base + off); off += 221184;
    unsigned short* Vb = (unsigned short*)(base + off); off += 393216;
    float* P  = (float*)(base + off); off += 442368;
    float* ST = (float*)(base + off); off += 4608;
    float* S1 = (float*)(base + off); off += 33177600;
    float* S2 = (float*)(base + off); off += 33177600;
    float* AM = (float*)(base + off); off += 33177600;
    size_t k1bBytes = (size_t)BS * C * HW * 2;       // 88,473,600
    size_t xtpBytes = (size_t)BS * 24 * XROWS * XCOLS * 16;  // 98,942,976
    unsigned short* k1b = nullptr;
    unsigned short* xTp = (unsigned short*)S1;       // alias tier: lifetime [k_xt..k_conv]
    int xtpSep = 0;
    if (ws_size >= off + k1bBytes) {
        k1b = (unsigned short*)(base + off); off += k1bBytes;
        if (ws_size >= off + xtpBytes) {
            xTp = (unsigned short*)(base + off); off += xtpBytes;
            xtpSep = 1;
        }
    }
    int writeF32 = (k1b == nullptr) ? 1 : 0;

    k_wfold<<<(NWQ + 255) / 256, 256, 0, stream>>>(key_w, bn1_g, bn1_v, Wq);
    k_xt<<<dim3(H, BS), 256, 0, stream>>>(x, xTp);
    k_pool<<<BS * C, 256, 0, stream>>>(x, P);
    k_val<<<BS, 256, 0, stream>>>(val_w, P, Vb);
    k_conv_mfma<<<dim3(H / 2, 3, BS), 256, 0, stream>>>(
        xTp, Wq, bn1_g, bn1_b, bn1_m, bn1_v, out, k1b, writeF32);
    k_scores_mfma<<<dim3((HW + SPX - 1) / SPX, BS), 256, 0, stream>>>(
        P, out, k1b, x, xtpSep ? xTp : nullptr, S1, S2);
    k_rowstats<<<BS * AN, 256, 0, stream>>>(S1, ST);
    k_fuse<<<dim3((HW + 255) / 256, BS), 256, 0, stream>>>(
        S1, ST, S2, att_w1, bn2_g, bn2_b, bn2_m, bn2_v, att_w2, att_b2, AM);
    k_out_mfma<<<dim3(HW / OPX, BS), 256, 0, stream>>>(AM, Vb, k1b, out);
}

// Round 9
// 456.978 us; speedup vs baseline: 11.9046x; 1.1432x over previous
//
#include <hip/hip_runtime.h>
#include <hip/hip_bf16.h>
#include <math.h>

#define BS 16
#define C 192
#define H 120
#define W 120
#define HW 14400
#define AN 36
#define MID 18
#define CPG 64
#define EPS 1e-5f
#define SPX 128
#define BPS 200
#define NWQ 13824   // 3g * 2cc * 9tap * 4hi * 64co units (16B each)
#define XROWS 122
#define XCOLS 132
#define OPX 64      // k_out pixels per block
#define WST 72      // k_out w LDS stride (shorts; 144B = 16B-aligned, bank-step 4)

typedef __attribute__((ext_vector_type(8))) short s16x8;
typedef __attribute__((ext_vector_type(4))) float f32x4;
typedef __attribute__((ext_vector_type(4))) unsigned short u16x4;

static __device__ __forceinline__ short f2bf(float f) {
    union { float f; unsigned u; } v; v.f = f;
    unsigned r = (v.u + 0x7FFF + ((v.u >> 16) & 1)) >> 16;
    return (short)r;
}
static __device__ __forceinline__ float bf2f(unsigned short u) {
    union { unsigned u; float f; } v; v.u = ((unsigned)u) << 16;
    return v.f;
}
static __device__ __forceinline__ s16x8 cvt8(float4 f0, float4 f1) {
    s16x8 v;
    v[0] = f2bf(f0.x); v[1] = f2bf(f0.y); v[2] = f2bf(f0.z); v[3] = f2bf(f0.w);
    v[4] = f2bf(f1.x); v[5] = f2bf(f1.y); v[6] = f2bf(f1.z); v[7] = f2bf(f1.w);
    return v;
}

// ------- fold BN1 into key_w, bf16, B-fragment layout -------
__global__ __launch_bounds__(256) void k_wfold(const float* __restrict__ kw,
                                               const float* __restrict__ g1,
                                               const float* __restrict__ v1,
                                               unsigned short* __restrict__ Wq) {
    int u = blockIdx.x * 256 + threadIdx.x;
    if (u >= NWQ) return;
    int gc = u / 2304, rem = u - gc * 2304;
    int g = gc >> 1, cc = gc & 1;
    int th = rem >> 6, co = rem & 63;
    int tap = th >> 2, hi = th & 3;
    int cog = g * 64 + co;
    float inv = g1[cog] * rsqrtf(v1[cog] + EPS);
    const float* wp = kw + ((size_t)cog * 64 + cc * 32 + hi * 8) * 9 + tap;
    s16x8 v;
    #pragma unroll
    for (int e = 0; e < 8; ++e) v[e] = f2bf(wp[e * 9] * inv);
    *(s16x8*)&Wq[(size_t)u * 8] = v;
}

// ------- xTp: x f32 [b,c,hw] -> bf16 [b][oct24][row 122][col 132][8], zero halo -------
__global__ __launch_bounds__(256) void k_xt(const float* __restrict__ x,
                                            unsigned short* __restrict__ xTp) {
    int y = blockIdx.x, b = blockIdx.y;
    int t = threadIdx.x;
    __shared__ unsigned short L[120 * 200];
    for (int u = t; u < 24 * 120; u += 256) {
        int oc = u / 120, px = u - oc * 120;
        const float* xp = x + ((size_t)b * C + oc * 8) * HW + y * W + px;
        s16x8 v;
        #pragma unroll
        for (int j = 0; j < 8; ++j) v[j] = f2bf(xp[(size_t)j * HW]);
        *(s16x8*)&L[px * 200 + oc * 8] = v;
    }
    __syncthreads();
    for (int u = t; u < 24 * XCOLS; u += 256) {
        int oc = u / XCOLS, p = u - oc * XCOLS;
        int px = p - 1;
        s16x8 v = {0, 0, 0, 0, 0, 0, 0, 0};
        if (px >= 0 && px < 120) v = *(const s16x8*)&L[px * 200 + oc * 8];
        *(s16x8*)&xTp[(((size_t)(b * 24 + oc)) * XROWS + (y + 1)) * XCOLS * 8 + p * 8] = v;
    }
    if (y == 0 || y == H - 1) {
        int r = (y == 0) ? 0 : XROWS - 1;
        s16x8 z = {0, 0, 0, 0, 0, 0, 0, 0};
        for (int u = t; u < 24 * XCOLS; u += 256) {
            int oc = u / XCOLS, p = u - oc * XCOLS;
            *(s16x8*)&xTp[(((size_t)(b * 24 + oc)) * XROWS + r) * XCOLS * 8 + p * 8] = z;
        }
    }
}

// ------- pool6 from bf16 xTp (L3-hot): P[b][c][36] f32 -------
__global__ __launch_bounds__(256) void k_pool_b(const unsigned short* __restrict__ xTp,
                                                float* __restrict__ P) {
    int oc = blockIdx.x, b = blockIdx.y;
    int t = threadIdx.x;
    __shared__ float Lp[240 * 24];   // [strip y*2+h][qq*8+e]
    const unsigned short* base =
        xTp + (((size_t)(b * 24 + oc)) * XROWS + 1) * XCOLS * 8 + 8;
    if (t < 240) {
        int y = t >> 1, h = t & 1;
        const unsigned short* row = base + (size_t)y * XCOLS * 8 + h * 60 * 8;
        float acc[3][8];
        #pragma unroll
        for (int qq = 0; qq < 3; ++qq)
            #pragma unroll
            for (int e = 0; e < 8; ++e) acc[qq][e] = 0.f;
        #pragma unroll
        for (int qq = 0; qq < 3; ++qq)
            for (int j = 0; j < 20; ++j) {
                s16x8 v = *(const s16x8*)&row[(qq * 20 + j) * 8];
                #pragma unroll
                for (int e = 0; e < 8; ++e) acc[qq][e] += bf2f((unsigned short)v[e]);
            }
        #pragma unroll
        for (int qq = 0; qq < 3; ++qq)
            #pragma unroll
            for (int e = 0; e < 8; ++e) Lp[t * 24 + qq * 8 + e] = acc[qq][e];
    }
    __syncthreads();
    if (t < 288) {
        int seg = t >> 3, e = t & 7;
        int yq = seg / 6, q = seg % 6;
        int h = q / 3, qq = q % 3;
        float s = 0.f;
        for (int j = 0; j < 20; ++j)
            s += Lp[((yq * 20 + j) * 2 + h) * 24 + qq * 8 + e];
        P[((size_t)b * C + oc * 8 + e) * AN + seg] = s * (1.f / 400.f);
    }
}

// ------- Vb[b][cc][64] bf16 = val_w @ pooled (a>=36 zero-padded) -------
__global__ __launch_bounds__(256) void k_val(const float* __restrict__ valw,
                                             const float* __restrict__ P,
                                             unsigned short* __restrict__ Vb) {
    int b = blockIdx.x;
    __shared__ float Pl[C * AN];
    int tid = threadIdx.x;
    for (int i = tid; i < C * AN; i += 256) Pl[i] = P[(size_t)b * C * AN + i];
    __syncthreads();
    for (int o = tid; o < C * 8; o += 256) {
        int cc = o >> 3, a8 = o & 7;
        s16x8 vv = {0, 0, 0, 0, 0, 0, 0, 0};
        #pragma unroll
        for (int j = 0; j < 8; ++j) {
            int a = a8 * 8 + j;
            if (a < AN) {
                float s = 0.f;
                for (int k = 0; k < C; ++k) s += valw[cc * C + k] * Pl[k * AN + a];
                vv[j] = f2bf(s);
            }
        }
        *(s16x8*)&Vb[((size_t)b * C + cc) * 64 + a8 * 8] = vv;
    }
}

// ------------- grouped 3x3 conv + BN1 + ReLU, implicit-GEMM MFMA -------------
__global__ __launch_bounds__(256, 4) void k_conv_mfma(
        const unsigned short* __restrict__ xTp, const unsigned short* __restrict__ Wq,
        const float* __restrict__ g1, const float* __restrict__ b1,
        const float* __restrict__ m1, const float* __restrict__ v1,
        float* __restrict__ k1f, unsigned short* __restrict__ k1b, int writeF32) {
    int yp = blockIdx.x, g = blockIdx.y, b = blockIdx.z;
    int y0 = yp * 2;
    int t = threadIdx.x;
    __shared__ short xl[(2048 + 2) * 8];

    int w = t >> 6, l = t & 63, lr = l & 15, hi = l >> 4;
    int ry = w >> 1, xh = w & 1;
    f32x4 acc[4][4];
    #pragma unroll
    for (int mt = 0; mt < 4; ++mt)
        #pragma unroll
        for (int nt = 0; nt < 4; ++nt)
            acc[mt][nt] = (f32x4){0.f, 0.f, 0.f, 0.f};

    for (int cc = 0; cc < 2; ++cc) {
        if (cc) __syncthreads();
        const unsigned short* xbase =
            xTp + ((size_t)((b * 24 + g * 8 + cc * 4) * XROWS) + y0) * XCOLS * 8;
        #pragma unroll
        for (int k = 0; k < 8; ++k) {
            int u = t + 256 * k;
            int run = u >> 7, p = u & 127;
            int oct = run >> 2, r = run & 3;
            s16x8 v = *(const s16x8*)&xbase[((size_t)(oct * XROWS + r)) * XCOLS * 8 + p * 8];
            *(s16x8*)&xl[u * 8] = v;
        }
        __syncthreads();
        const s16x8* wq = (const s16x8*)Wq + (size_t)(g * 2 + cc) * 2304;
        s16x8 Bn[4];
        #pragma unroll
        for (int nt = 0; nt < 4; ++nt) Bn[nt] = wq[hi * 64 + nt * 16 + lr];
        #pragma unroll
        for (int tap = 0; tap < 9; ++tap) {
            int ky = tap / 3, kx = tap % 3;
            s16x8 Bc[4];
            #pragma unroll
            for (int nt = 0; nt < 4; ++nt) Bc[nt] = Bn[nt];
            if (tap < 8) {
                #pragma unroll
                for (int nt = 0; nt < 4; ++nt)
                    Bn[nt] = wq[((tap + 1) * 4 + hi) * 64 + nt * 16 + lr];
            }
            s16x8 A[4];
            #pragma unroll
            for (int mt = 0; mt < 4; ++mt) {
                int col = xh * 64 + mt * 16 + lr + kx;
                A[mt] = *(const s16x8*)&xl[((hi * 4 + ry + ky) * 128 + col) * 8];
            }
            #pragma unroll
            for (int mt = 0; mt < 4; ++mt)
                #pragma unroll
                for (int nt = 0; nt < 4; ++nt)
                    acc[mt][nt] = __builtin_amdgcn_mfma_f32_16x16x32_bf16(
                        A[mt], Bc[nt], acc[mt][nt], 0, 0, 0);
        }
    }
    int y = y0 + ry;
    #pragma unroll
    for (int nt = 0; nt < 4; ++nt) {
        int cog = g * CPG + nt * 16 + lr;
        float inv = g1[cog] * rsqrtf(v1[cog] + EPS);
        float beta = b1[cog] - m1[cog] * inv;
        #pragma unroll
        for (int mt = 0; mt < 4; ++mt) {
            int xcol = xh * 64 + mt * 16 + hi * 4;
            if (xcol >= 120) continue;
            float r0 = fmaxf(acc[mt][nt][0] + beta, 0.f);
            float r1 = fmaxf(acc[mt][nt][1] + beta, 0.f);
            float r2 = fmaxf(acc[mt][nt][2] + beta, 0.f);
            float r3 = fmaxf(acc[mt][nt][3] + beta, 0.f);
            size_t base = ((size_t)(b * C + cog)) * HW + y * W + xcol;
            if (writeF32) {
                *(float4*)&k1f[base] = make_float4(r0, r1, r2, r3);
            } else {
                u16x4 q;
                q[0] = (unsigned short)f2bf(r0); q[1] = (unsigned short)f2bf(r1);
                q[2] = (unsigned short)f2bf(r2); q[3] = (unsigned short)f2bf(r3);
                *(u16x4*)&k1b[base] = q;
            }
        }
    }
}

// ------- scores via MFMA: S1 = agent . k1view, S2 = agent . xview -------
__global__ __launch_bounds__(256, 3) void k_scores_mfma(
        const float* __restrict__ Pp, const float* __restrict__ k1f,
        const unsigned short* __restrict__ k1b, const float* __restrict__ x,
        const unsigned short* __restrict__ xTp,
        float* __restrict__ S1, float* __restrict__ S2) {
    int b = blockIdx.y;
    int n0 = blockIdx.x * SPX;
    int t = threadIdx.x;
    int w = t >> 6, l = t & 63, lr = l & 15, hi = l >> 4;
    __shared__ short Bp[SPX * BPS];

    s16x8 afr[3][6];
    const float* ab = Pp + (size_t)b * (C * AN);
    #pragma unroll
    for (int mt = 0; mt < 3; ++mt) {
        int row = mt * 16 + lr;
        #pragma unroll
        for (int kc = 0; kc < 6; ++kc) {
            s16x8 v = {0, 0, 0, 0, 0, 0, 0, 0};
            if (row < AN) {
                const float4* ap = (const float4*)(ab + row * C + kc * 32 + hi * 8);
                v = cvt8(ap[0], ap[1]);
            }
            afr[mt][kc] = v;
        }
    }

    #pragma unroll 1
    for (int s = 0; s < 2; ++s) {
        __syncthreads();
        if (s == 0 && k1b) {
            const unsigned short* src = k1b + (size_t)b * C * HW + (size_t)n0 * C;
            for (int i = t; i < SPX * 24; i += 256) {
                int row = i / 24, o = i - row * 24;
                s16x8 v = {0, 0, 0, 0, 0, 0, 0, 0};
                if (n0 + row < HW) v = *(const s16x8*)&src[row * C + o * 8];
                *(s16x8*)&Bp[row * BPS + o * 8] = v;
            }
        } else if (s == 1 && xTp) {
            for (int i = t; i < SPX * 24; i += 256) {
                int row = i / 24, oc = i - row * 24;
                int n = n0 + row;
                s16x8 v = {0, 0, 0, 0, 0, 0, 0, 0};
                if (n < HW) {
                    int yy = n / 120, xx = n - yy * 120;
                    v = *(const s16x8*)&xTp[(((size_t)(b * 24 + oc)) * XROWS + yy + 1) *
                                            XCOLS * 8 + (xx + 1) * 8];
                }
                *(s16x8*)&Bp[row * BPS + oc * 8] = v;
            }
        } else {
            const float* sf = (s == 0) ? k1f : x;
            const float4* src = (const float4*)(sf + (size_t)b * C * HW + (size_t)n0 * C);
            for (int i = t; i < SPX * 24; i += 256) {
                int row = i / 24, c8 = (i - row * 24) * 8;
                s16x8 v = {0, 0, 0, 0, 0, 0, 0, 0};
                if (n0 + row < HW)
                    v = cvt8(src[row * 48 + c8 / 4], src[row * 48 + c8 / 4 + 1]);
                *(s16x8*)&Bp[row * BPS + c8] = v;
            }
        }
        __syncthreads();
        f32x4 acc[3][2];
        #pragma unroll
        for (int mt = 0; mt < 3; ++mt)
            #pragma unroll
            for (int pt = 0; pt < 2; ++pt)
                acc[mt][pt] = (f32x4){0.f, 0.f, 0.f, 0.f};
        #pragma unroll
        for (int kc = 0; kc < 6; ++kc) {
            s16x8 bf[2];
            #pragma unroll
            for (int pt = 0; pt < 2; ++pt) {
                int px = (w * 2 + pt) * 16 + lr;
                bf[pt] = *(const s16x8*)&Bp[px * BPS + kc * 32 + hi * 8];
            }
            #pragma unroll
            for (int mt = 0; mt < 3; ++mt)
                #pragma unroll
                for (int pt = 0; pt < 2; ++pt)
                    acc[mt][pt] = __builtin_amdgcn_mfma_f32_16x16x32_bf16(
                        afr[mt][kc], bf[pt], acc[mt][pt], 0, 0, 0);
        }
        float* dst = (s == 0 ? S1 : S2) + (size_t)b * AN * HW + n0;
        #pragma unroll
        for (int mt = 0; mt < 3; ++mt)
            #pragma unroll
            for (int pt = 0; pt < 2; ++pt) {
                int px = (w * 2 + pt) * 16 + lr;
                if (n0 + px >= HW) continue;
                #pragma unroll
                for (int r = 0; r < 4; ++r) {
                    int a = mt * 16 + hi * 4 + r;
                    if (a < AN) dst[(size_t)a * HW + px] = acc[mt][pt][r];
                }
            }
    }
}

// ---------------- per-row (b,a) stats of S1: max and 1/sum(exp) ----------------
__global__ __launch_bounds__(256) void k_rowstats(const float* __restrict__ S,
                                                  float* __restrict__ stats) {
    int row = blockIdx.x;
    const float* p = S + (size_t)row * HW;
    int tid = threadIdx.x;
    __shared__ float red[4];
    float m = -1e30f;
    for (int i = tid; i < HW / 4; i += 256) {
        float4 v = ((const float4*)p)[i];
        m = fmaxf(m, fmaxf(fmaxf(v.x, v.y), fmaxf(v.z, v.w)));
    }
    #pragma unroll
    for (int off = 32; off > 0; off >>= 1) m = fmaxf(m, __shfl_down(m, off, 64));
    if ((tid & 63) == 0) red[tid >> 6] = m;
    __syncthreads();
    m = fmaxf(fmaxf(red[0], red[1]), fmaxf(red[2], red[3]));
    __syncthreads();
    float s = 0.f;
    for (int i = tid; i < HW / 4; i += 256) {
        float4 v = ((const float4*)p)[i];
        s += __expf(v.x - m) + __expf(v.y - m) + __expf(v.z - m) + __expf(v.w - m);
    }
    #pragma unroll
    for (int off = 32; off > 0; off >>= 1) s += __shfl_down(s, off, 64);
    if ((tid & 63) == 0) red[tid >> 6] = s;
    __syncthreads();
    if (tid == 0) {
        stats[row] = m;
        stats[576 + row] = 1.f / (red[0] + red[1] + red[2] + red[3]);
    }
}

// ------- fused: softmax(S1) via stats, softmax36(S2), conv1+BN2+ReLU, conv2 -------
__global__ __launch_bounds__(256) void k_fuse(const float* __restrict__ A1,
                                              const float* __restrict__ stats,
                                              const float* __restrict__ S2,
                                              const float* __restrict__ w1,
                                              const float* __restrict__ g2,
                                              const float* __restrict__ b2,
                                              const float* __restrict__ m2,
                                              const float* __restrict__ v2,
                                              const float* __restrict__ w2,
                                              const float* __restrict__ bias2,
                                              unsigned short* __restrict__ AMb) {
    int b = blockIdx.y;
    int tid = threadIdx.x;
    int N = blockIdx.x * 256 + tid;
    __shared__ float W1f[MID * 72];
    __shared__ float b1f[MID];
    __shared__ float W2m[AN * MID];
    __shared__ float b2m[AN];
    __shared__ float sm_m[AN], sm_ri[AN];
    for (int i = tid; i < MID * 72; i += 256) {
        int m = i / 72;
        W1f[i] = w1[i] * (g2[m] * rsqrtf(v2[m] + EPS));
    }
    if (tid < MID) {
        float inv = g2[tid] * rsqrtf(v2[tid] + EPS);
        b1f[tid] = b2[tid] - m2[tid] * inv;
    }
    for (int i = tid; i < AN * MID; i += 256) {
        int a = i / MID, m = i % MID;
        float s = 0.f;
        #pragma unroll
        for (int k = 0; k < 9; ++k) s += w2[(a * 9 + k) * MID + m];
        W2m[i] = s * (1.f / 9.f);
    }
    if (tid < AN) {
        float s = 0.f;
        #pragma unroll
        for (int k = 0; k < 9; ++k) s += bias2[tid * 9 + k];
        b2m[tid] = s * (1.f / 9.f);
        sm_m[tid] = stats[b * AN + tid];
        sm_ri[tid] = stats[576 + b * AN + tid];
    }
    __syncthreads();
    if (N >= HW) return;
    float yv[72];
    const float* a1p = A1 + (size_t)b * AN * HW + N;
    #pragma unroll
    for (int j = 0; j < AN; ++j)
        yv[j] = __expf(a1p[(size_t)j * HW] - sm_m[j]) * sm_ri[j];
    const float* s2p = S2 + (size_t)b * AN * HW + N;
    float mx = -1e30f;
    #pragma unroll
    for (int j = 0; j < AN; ++j) {
        float v = s2p[(size_t)j * HW];
        yv[AN + j] = v;
        mx = fmaxf(mx, v);
    }
    float ssum = 0.f;
    #pragma unroll
    for (int j = 0; j < AN; ++j) {
        float e = __expf(yv[AN + j] - mx);
        yv[AN + j] = e;
        ssum += e;
    }
    float rs = 1.f / ssum;
    #pragma unroll
    for (int j = 0; j < AN; ++j) yv[AN + j] *= rs;
    float t[MID];
    #pragma unroll
    for (int m = 0; m < MID; ++m) {
        float a = b1f[m];
        #pragma unroll
        for (int j = 0; j < 72; ++j) a += W1f[m * 72 + j] * yv[j];
        t[m] = a > 0.f ? a : 0.f;
    }
    unsigned short* amp = AMb + (size_t)b * AN * HW + N;
    #pragma unroll
    for (int a = 0; a < AN; ++a) {
        float acc = b2m[a];
        #pragma unroll
        for (int m = 0; m < MID; ++m) acc += W2m[a * MID + m] * t[m];
        amp[(size_t)a * HW] = (unsigned short)f2bf(acc);
    }
}

// ------- out via MFMA: out[cc][n] = sum_a softmax36(AMb window)[a]*Vb[cc][a] + k1 -------
__global__ __launch_bounds__(256) void k_out_mfma(const unsigned short* __restrict__ AMb,
                                                  const unsigned short* __restrict__ Vb,
                                                  const unsigned short* __restrict__ k1b,
                                                  float* __restrict__ outp) {
    int b = blockIdx.y;
    int N0 = blockIdx.x * OPX;
    int t = threadIdx.x;
    __shared__ float smemf[4 * 1088];     // 17408 B; wl aliases the front 9216 B
    short* wl = (short*)smemf;

    // phase 1: per-pixel window softmax, 4 lanes/pixel (bf16 AM)
    {
        int p = t >> 2, q = t & 3;
        int N = N0 + p;
        int a = N / 400;
        int n0w = (N - a * 400) * AN;
        const unsigned short* amp = AMb + ((size_t)b * AN + a) * HW + n0w;
        const int qoff = (q == 0) ? 0 : (q == 1) ? 12 : (q == 2) ? 20 : 32;
        const int qn4 = (q == 0) ? 3 : (q == 1) ? 2 : (q == 2) ? 3 : 1;
        float vals[12];
        const u16x4* ap = (const u16x4*)(amp + qoff);
        #pragma unroll
        for (int i = 0; i < 3; ++i) {
            if (i < qn4) {
                u16x4 v = ap[i];
                vals[i * 4 + 0] = bf2f(v[0]); vals[i * 4 + 1] = bf2f(v[1]);
                vals[i * 4 + 2] = bf2f(v[2]); vals[i * 4 + 3] = bf2f(v[3]);
            }
        }
        int cnt = qn4 * 4;
        float m = -1e30f;
        #pragma unroll
        for (int i = 0; i < 12; ++i) if (i < cnt) m = fmaxf(m, vals[i]);
        m = fmaxf(m, __shfl_xor(m, 1, 64));
        m = fmaxf(m, __shfl_xor(m, 2, 64));
        float s = 0.f;
        #pragma unroll
        for (int i = 0; i < 12; ++i)
            if (i < cnt) { vals[i] = __expf(vals[i] - m); s += vals[i]; }
        s += __shfl_xor(s, 1, 64);
        s += __shfl_xor(s, 2, 64);
        float rs = 1.f / s;
        #pragma unroll
        for (int i = 0; i < 12; ++i)
            if (i < cnt) wl[p * WST + qoff + i] = f2bf(vals[i] * rs);
        if (q == 3) {
            #pragma unroll
            for (int i = 36; i < 64; ++i) wl[p * WST + i] = 0;
        }
    }
    __syncthreads();

    // phase 2: GEMM 192cc x 64px, K=36 (padded 64; both pads zero)
    int w = t >> 6, l = t & 63, lr = l & 15, hi = l >> 4;
    int cc0 = w * 48;
    const s16x8* vb = (const s16x8*)(Vb + (size_t)b * C * 64);
    s16x8 Af[3][2];
    #pragma unroll
    for (int mt = 0; mt < 3; ++mt)
        #pragma unroll
        for (int ch = 0; ch < 2; ++ch)
            Af[mt][ch] = vb[(cc0 + mt * 16 + lr) * 8 + ch * 4 + hi];
    f32x4 acc[3][4];
    #pragma unroll
    for (int mt = 0; mt < 3; ++mt)
        #pragma unroll
        for (int pt = 0; pt < 4; ++pt)
            acc[mt][pt] = (f32x4){0.f, 0.f, 0.f, 0.f};
    #pragma unroll
    for (int pt = 0; pt < 4; ++pt) {
        s16x8 Bf[2];
        #pragma unroll
        for (int ch = 0; ch < 2; ++ch)
            Bf[ch] = *(const s16x8*)&wl[(pt * 16 + lr) * WST + ch * 32 + hi * 8];
        #pragma unroll
        for (int ch = 0; ch < 2; ++ch)
            #pragma unroll
            for (int mt = 0; mt < 3; ++mt)
                acc[mt][pt] = __builtin_amdgcn_mfma_f32_16x16x32_bf16(
                    Af[mt][ch], Bf[ch], acc[mt][pt], 0, 0, 0);
    }
    __syncthreads();   // wl no longer needed; reuse smem as per-wave transpose tiles

    // epilogue: per-wave LDS transpose -> vectorized k1 residual + stores
    float* T = smemf + (size_t)w * 1088;   // 16 rows x 68 floats
    #pragma unroll
    for (int mt = 0; mt < 3; ++mt) {
        #pragma unroll
        for (int pt = 0; pt < 4; ++pt)
            #pragma unroll
            for (int r = 0; r < 4; ++r)
                T[(hi * 4 + r) * 68 + pt * 16 + lr] = acc[mt][pt][r];
        // same-wave DS ordering: writes above complete before reads below
        #pragma unroll
        for (int pass = 0; pass < 4; ++pass) {
            int ccr = pass * 4 + hi;
            int px4 = (l & 15) * 4;
            float4 vv = *(float4*)&T[ccr * 68 + px4];
            int cc = cc0 + mt * 16 + ccr;
            size_t idx = ((size_t)(b * C + cc)) * HW + N0 + px4;
            float4 res;
            if (k1b) {
                u16x4 kk = *(const u16x4*)&k1b[idx];
                res = make_float4(bf2f(kk[0]), bf2f(kk[1]), bf2f(kk[2]), bf2f(kk[3]));
            } else {
                res = *(float4*)&outp[idx];
            }
            vv.x += res.x; vv.y += res.y; vv.z += res.z; vv.w += res.w;
            *(float4*)&outp[idx] = vv;
        }
    }
}

extern "C" void kernel_launch(void* const* d_in, const int* in_sizes, int n_in,
                              void* d_out, int out_size, void* d_ws, size_t ws_size,
                              hipStream_t stream) {
    const float* x      = (const float*)d_in[0];
    const float* key_w  = (const float*)d_in[1];
    const float* bn1_g  = (const float*)d_in[2];
    const float* bn1_b  = (const float*)d_in[3];
    const float* bn1_m  = (const float*)d_in[4];
    const float* bn1_v  = (const float*)d_in[5];
    const float* val_w  = (const float*)d_in[6];
    const float* att_w1 = (const float*)d_in[7];
    const float* bn2_g  = (const float*)d_in[8];
    const float* bn2_b  = (const float*)d_in[9];
    const float* bn2_m  = (const float*)d_in[10];
    const float* bn2_v  = (const float*)d_in[11];
    const float* att_w2 = (const float*)d_in[12];
    const float* att_b2 = (const float*)d_in[13];
    float* out = (float*)d_out;

    unsigned char* base = (unsigned char*)d_ws;
    size_t off = 0;
    unsigned short* Wq = (unsigned short*)(base + off); off += 221184;
    unsigned short* Vb = (unsigned short*)(base + off); off += 393216;
    float* P  = (float*)(base + off); off += 442368;
    float* ST = (float*)(base + off); off += 4608;
    float* S1 = (float*)(base + off); off += 33177600;
    float* S2 = (float*)(base + off); off += 33177600;
    unsigned short* AMb = (unsigned short*)(base + off); off += 33177600;  // uses half
    size_t k1bBytes = (size_t)BS * C * HW * 2;               // 88,473,600
    size_t xtpBytes = (size_t)BS * 24 * XROWS * XCOLS * 16;  // 98,942,976
    unsigned short* k1b = nullptr;
    unsigned short* xTp = (unsigned short*)S1;   // alias tier: lifetime [k_xt..k_conv]
    int xtpSep = 0;
    if (ws_size >= off + k1bBytes) {
        k1b = (unsigned short*)(base + off); off += k1bBytes;
        if (ws_size >= off + xtpBytes) {
            xTp = (unsigned short*)(base + off); off += xtpBytes;
            xtpSep = 1;
        }
    }
    int writeF32 = (k1b == nullptr) ? 1 : 0;

    k_wfold<<<(NWQ + 255) / 256, 256, 0, stream>>>(key_w, bn1_g, bn1_v, Wq);
    k_xt<<<dim3(H, BS), 256, 0, stream>>>(x, xTp);
    k_pool_b<<<dim3(24, BS), 256, 0, stream>>>(xTp, P);
    k_val<<<BS, 256, 0, stream>>>(val_w, P, Vb);
    k_conv_mfma<<<dim3(H / 2, 3, BS), 256, 0, stream>>>(
        xTp, Wq, bn1_g, bn1_b, bn1_m, bn1_v, out, k1b, writeF32);
    k_scores_mfma<<<dim3((HW + SPX - 1) / SPX, BS), 256, 0, stream>>>(
        P, out, k1b, x, xtpSep ? xTp : nullptr, S1, S2);
    k_rowstats<<<BS * AN, 256, 0, stream>>>(S1, ST);
    k_fuse<<<dim3((HW + 255) / 256, BS), 256, 0, stream>>>(
        S1, ST, S2, att_w1, bn2_g, bn2_b, bn2_m, bn2_v, att_w2, att_b2, AMb);
    k_out_mfma<<<dim3(HW / OPX, BS), 256, 0, stream>>>(AMb, Vb, k1b, out);
}